// Round 10
// baseline (228.640 us; speedup 1.0000x reference)
//
#include <hip/hip_runtime.h>
#include <hip/hip_bf16.h>
#include <cstdint>

#define DEV __device__ __forceinline__

typedef __attribute__((ext_vector_type(8))) short short8;
typedef __attribute__((ext_vector_type(4))) float f32x4;
typedef __attribute__((ext_vector_type(4))) unsigned short us4;
typedef __attribute__((ext_vector_type(8))) unsigned short us8;

DEV unsigned short f2bf(float x) {
    unsigned int u = __float_as_uint(x);
    unsigned int r = (u + 0x7FFFu + ((u >> 16) & 1u)) >> 16;
    return (unsigned short)r;
}
DEV float bf2f(unsigned short h) { return __uint_as_float(((unsigned int)h) << 16); }

// async global->LDS, 16B per lane; LDS dest is wave-uniform base + lane*16 (HW rule)
DEV void gld_lds16(const unsigned short* g, unsigned short* l) {
    __builtin_amdgcn_global_load_lds(
        (const __attribute__((address_space(1))) unsigned int*)g,
        (__attribute__((address_space(3))) unsigned int*)l, 16, 0, 0);
}

// problem sizes
#define LL 4096
#define DM 256
#define DH 128
#define SB_TOT 8       // 2 streams * 4 batch
#define CH1 32         // scan chunk length
#define NCH 128        // LL / CH1
#define LOG2E 1.44269504088896f

// P/H layout: float offset PH(sb,ch,n4,d) = (((sb*NCH+ch)*4 + n4)*128 + d)*4
// -> lane d consecutive => fully coalesced quad stores/loads.

// ---------------- prep: fp32 -> bf16 (u, in_proj, out_proj) + fused proj weight Wb ----------------
__global__ __launch_bounds__(256) void prep_kernel(
    const float* __restrict__ u0, const float* __restrict__ u1,
    const float* __restrict__ inw, const float* __restrict__ outw,
    const float* __restrict__ xpw, const float* __restrict__ dtw,
    unsigned short* __restrict__ ubf, unsigned short* __restrict__ wbi,
    unsigned short* __restrict__ wbo, unsigned short* __restrict__ Wb)
{
    int gid = blockIdx.x * 256 + threadIdx.x;
    int i = gid * 4;
    if (i < 4194304) {
        f32x4 v = *(const f32x4*)&u0[i];
        us4 r = { f2bf(v.x), f2bf(v.y), f2bf(v.z), f2bf(v.w) };
        *(us4*)&ubf[i] = r;
    } else if (i < 8388608) {
        int j = i - 4194304;
        f32x4 v = *(const f32x4*)&u1[j];
        us4 r = { f2bf(v.x), f2bf(v.y), f2bf(v.z), f2bf(v.w) };
        *(us4*)&ubf[4194304 + j] = r;
    } else if (i < 8454144) {
        int j = i - 8388608;
        f32x4 v = *(const f32x4*)&inw[j];
        us4 r = { f2bf(v.x), f2bf(v.y), f2bf(v.z), f2bf(v.w) };
        *(us4*)&wbi[j] = r;
    } else if (i < 8519680) {
        int j = i - 8454144;
        f32x4 v = *(const f32x4*)&outw[j];
        us4 r = { f2bf(v.x), f2bf(v.y), f2bf(v.z), f2bf(v.w) };
        *(us4*)&wbo[j] = r;
    } else if (i < 8540160) {
        int j = i - 8519680;            // 0..20476, step 4
        int n = j >> 7, k0 = j & 127;
        if (n < 128) {
            float a0 = 0.f, a1 = 0.f, a2 = 0.f, a3 = 0.f;
            const float* dw = dtw + n * 16;
            #pragma unroll
            for (int r = 0; r < 16; ++r) {
                float w = dw[r];
                const float* xr = xpw + r * 128 + k0;
                a0 = fmaf(w, xr[0], a0);
                a1 = fmaf(w, xr[1], a1);
                a2 = fmaf(w, xr[2], a2);
                a3 = fmaf(w, xr[3], a3);
            }
            us4 rr = { f2bf(a0), f2bf(a1), f2bf(a2), f2bf(a3) };
            *(us4*)&Wb[n * 128 + k0] = rr;
        } else {
            f32x4 v = *(const f32x4*)&xpw[(n - 112) * 128 + k0];
            us4 rr = { f2bf(v.x), f2bf(v.y), f2bf(v.z), f2bf(v.w) };
            *(us4*)&Wb[n * 128 + k0] = rr;
        }
    }
}

// ---------------- bf16 MFMA GEMM (m97 structure): C[M,N] = A[M,K] * B[N,K]^T, K=N=256 ----------------
template<int F32OUT>
__global__ __launch_bounds__(256) void gemm_bt(
    const unsigned short* __restrict__ A, const unsigned short* __restrict__ B,
    float* __restrict__ Cf, unsigned short* __restrict__ Cb)
{
    __shared__ __align__(16) unsigned short As[128 * 32];
    __shared__ __align__(16) unsigned short Bs[128 * 32];
    const int t = threadIdx.x;
    const int m0 = blockIdx.x * 128, n0 = blockIdx.y * 128;
    const int lane = t & 63, wv = t >> 6;
    const int wm = (wv & 1) * 64, wn = (wv >> 1) * 64;
    const int lr = lane & 15, lk = (lane >> 4) * 8;
    const int srow = lane >> 2, scol = (lane & 3) * 8;

    f32x4 acc[4][4] = {};
    for (int kt = 0; kt < 8; ++kt) {
        const int k0 = kt * 32;
        #pragma unroll
        for (int h = 0; h < 2; ++h) {
            const int c = wv + h * 4;
            const unsigned short* ga = A + (size_t)(m0 + c * 16 + srow) * 256 + k0 + scol;
            const unsigned short* gb = B + (size_t)(n0 + c * 16 + srow) * 256 + k0 + scol;
            gld_lds16(ga, &As[c * 512]);
            gld_lds16(gb, &Bs[c * 512]);
        }
        __syncthreads();
        short8 av[4], bv[4];
        #pragma unroll
        for (int i = 0; i < 4; ++i) av[i] = *(const short8*)&As[(wm + i * 16 + lr) * 32 + lk];
        #pragma unroll
        for (int i = 0; i < 4; ++i) bv[i] = *(const short8*)&Bs[(wn + i * 16 + lr) * 32 + lk];
        #pragma unroll
        for (int i = 0; i < 4; ++i)
            #pragma unroll
            for (int j = 0; j < 4; ++j)
                acc[i][j] = __builtin_amdgcn_mfma_f32_16x16x32_bf16(av[i], bv[j], acc[i][j], 0, 0, 0);
        __syncthreads();
    }
    #pragma unroll
    for (int i = 0; i < 4; ++i) {
        #pragma unroll
        for (int j = 0; j < 4; ++j) {
            int r0 = m0 + wm + i * 16 + (lane >> 4) * 4;
            int cc = n0 + wn + j * 16 + lr;
            #pragma unroll
            for (int r = 0; r < 4; ++r) {
                float v = acc[i][j][r];
                if (F32OUT) Cf[(size_t)(r0 + r) * 256 + cc] = v;
                else        Cb[(size_t)(r0 + r) * 256 + cc] = f2bf(v);
            }
        }
    }
}

// ---------------- fused depthwise conv + SiLU + proj MFMA + softplus + scan-p1 ----------------
// BM=32, grid 1024. Conv weights hoisted to registers (g,c are i-loop-invariant).
// Scan tail all-LDS; P/H stores coalesced via [sb][ch][n4][d][4] layout.
template<int FUSE_SCAN>
__global__ __launch_bounds__(256) void convproj_k(
    const unsigned short* __restrict__ xz, const unsigned short* __restrict__ Wb,
    const float* __restrict__ wx, const float* __restrict__ wz,
    const float* __restrict__ dtb, const float* __restrict__ alog,
    float* __restrict__ xf, unsigned short* __restrict__ catb,
    float* __restrict__ delta, float* __restrict__ BC,
    float* __restrict__ P, float* __restrict__ H)
{
    // smem: [0:16896) union{ As[32][136] bf16 (8704B) | dl_s[32][132] f32 }
    //       [16896:33792) xf_s[32][132] f32 ; [33792:35840) bc_s[32][16] f32
    __shared__ __align__(16) char smem[35840];
    unsigned short* As = (unsigned short*)smem;
    float* dl_s = (float*)smem;
    float* xf_s = (float*)(smem + 16896);
    float* bc_s = (float*)(smem + 33792);
    const int t = threadIdx.x;
    // bijective XCD-aligned mapping (rows this block reads were produced on its XCD)
    const int kk = blockIdx.x & 7, yy = blockIdx.x >> 3;
    const int m0 = (4 * kk + (yy & 3) + 32 * (yy >> 2)) * 32;

    // conv: g,c invariant across the 4 row-iterations -> hoist weight loads
    const int gg = t & 31;
    const bool isx = gg < 16;
    const int c = (isx ? gg : gg - 16) * 8;
    const float* wp = isx ? wx : wz;
    float wreg[24];
    #pragma unroll
    for (int j = 0; j < 6; ++j) *(f32x4*)&wreg[j * 4] = *(const f32x4*)(wp + c * 3 + j * 4);
    #pragma unroll
    for (int i = 0; i < 4; ++i) {
        int r = (t >> 5) + i * 8;
        int gr = m0 + r;
        int l = gr & 4095;
        const unsigned short* bp = xz + (size_t)gr * 256 + (isx ? c : 128 + c);
        us8 zz = (us8)0;
        us8 vm = (l > 0)    ? *(const us8*)(bp - 256) : zz;
        us8 v0 = *(const us8*)bp;
        us8 vp = (l < 4095) ? *(const us8*)(bp + 256) : zz;
        float o[8];
        #pragma unroll
        for (int j = 0; j < 8; ++j) {
            float v = bf2f(vm[j]) * wreg[j * 3] + bf2f(v0[j]) * wreg[j * 3 + 1]
                    + bf2f(vp[j]) * wreg[j * 3 + 2];
            v = v / (1.f + __expf(-v));
            o[j] = v;
        }
        us8 rb8 = { f2bf(o[0]), f2bf(o[1]), f2bf(o[2]), f2bf(o[3]),
                    f2bf(o[4]), f2bf(o[5]), f2bf(o[6]), f2bf(o[7]) };
        if (isx) {
            *(us8*)&As[r * 136 + c] = rb8;
            *(f32x4*)&xf_s[r * 132 + c]     = *(f32x4*)&o[0];
            *(f32x4*)&xf_s[r * 132 + c + 4] = *(f32x4*)&o[4];
            *(f32x4*)&xf[(size_t)gr * 128 + c]     = *(f32x4*)&o[0];
            *(f32x4*)&xf[(size_t)gr * 128 + c + 4] = *(f32x4*)&o[4];
        } else {
            *(us8*)&catb[(size_t)gr * 256 + 128 + c] = rb8;
        }
    }
    __syncthreads();
    const int lane = t & 63, wv = t >> 6;
    const int lr = lane & 15, lk = (lane >> 4) * 8;
    const int rt = (wv & 1) * 16;        // row tile base
    const int jbase = (wv >> 1) * 5;     // col-tile base (0 or 5)
    f32x4 acc[5] = {};
    #pragma unroll
    for (int kt = 0; kt < 4; ++kt) {
        const int k0 = kt * 32;
        short8 av = *(const short8*)&As[(rt + lr) * 136 + k0 + lk];
        #pragma unroll
        for (int j = 0; j < 5; ++j) {
            short8 bv = *(const short8*)(Wb + ((jbase + j) * 16 + lr) * 128 + k0 + lk);
            acc[j] = __builtin_amdgcn_mfma_f32_16x16x32_bf16(av, bv, acc[j], 0, 0, 0);
        }
    }
    __syncthreads();   // As dead -> dl_s may overlay it
    const int r0 = (lane >> 4) * 4;
    #pragma unroll
    for (int j = 0; j < 5; ++j) {
        int jj = jbase + j;
        int col = jj * 16 + lr;
        #pragma unroll
        for (int r = 0; r < 4; ++r) {
            float v = acc[j][r];
            int lrow = rt + r0 + r;
            size_t row = (size_t)m0 + lrow;
            if (jj < 8) {
                float x = v + dtb[col];
                float sp = (x > 20.f) ? x : __logf(1.f + __expf(x));
                delta[row * 128 + col] = sp;
                if (FUSE_SCAN) dl_s[lrow * 132 + col] = sp;
            } else {
                BC[row * 32 + (col - 128)] = v;
                if (FUSE_SCAN && jj == 8) bc_s[lrow * 16 + lr] = v;   // B rows for scan
            }
        }
    }
    if (!FUSE_SCAN) return;

    // ---- scan phase-1 for this block's chunk; n split across thread halves; all-LDS reads ----
    __syncthreads();
    const int hh = t >> 7, tl = t & 127;
    const int sb = m0 >> 12;
    const int ch = (m0 & 4095) >> 5;
    float Ar[8];
    #pragma unroll
    for (int n = 0; n < 8; ++n) Ar[n] = -__expf(alog[tl * 16 + hh * 8 + n]) * LOG2E;
    float h[8], p[8];
    #pragma unroll
    for (int n = 0; n < 8; ++n) { h[n] = 0.f; p[n] = 1.f; }
    #pragma unroll 4
    for (int i = 0; i < CH1; ++i) {
        float dt = dl_s[i * 132 + tl];
        float du = dt * xf_s[i * 132 + tl];
        float bl[8];
        *(f32x4*)&bl[0] = *(const f32x4*)&bc_s[i * 16 + hh * 8];
        *(f32x4*)&bl[4] = *(const f32x4*)&bc_s[i * 16 + hh * 8 + 4];
        #pragma unroll
        for (int n = 0; n < 8; ++n) {
            float a = exp2f(dt * Ar[n]);
            h[n] = fmaf(a, h[n], du * bl[n]);
            p[n] *= a;
        }
    }
    // coalesced quad stores: PH(sb,ch,n4,d) with d = tl consecutive
    size_t qb = (((size_t)sb * NCH + ch) * 4) * 512 + (size_t)tl * 4;
    f32x4 pv0 = { p[0], p[1], p[2], p[3] };
    f32x4 pv1 = { p[4], p[5], p[6], p[7] };
    f32x4 hv0 = { h[0], h[1], h[2], h[3] };
    f32x4 hv1 = { h[4], h[5], h[6], h[7] };
    *(f32x4*)&P[qb + (size_t)(2 * hh) * 512]     = pv0;
    *(f32x4*)&P[qb + (size_t)(2 * hh + 1) * 512] = pv1;
    *(f32x4*)&H[qb + (size_t)(2 * hh) * 512]     = hv0;
    *(f32x4*)&H[qb + (size_t)(2 * hh + 1) * 512] = hv1;
}

// ---------------- selective scan, chunked 3-phase (standalone p1 = fallback) ----------------
__global__ __launch_bounds__(128) void scan_p1(
    const float* __restrict__ delta, const float* __restrict__ xf,
    const float* __restrict__ BC, const float* __restrict__ alog,
    float* __restrict__ P, float* __restrict__ H)
{
    __shared__ float b_s[CH1 * 16];
    int t = threadIdx.x;                 // d channel
    int ch = blockIdx.x, sb = blockIdx.y;
    size_t rb = (size_t)sb * LL + (size_t)ch * CH1;
    {
        int row = t >> 2, c4 = (t & 3) * 4;
        *(f32x4*)&b_s[row * 16 + c4] = *(const f32x4*)&BC[(rb + row) * 32 + c4];
    }
    __syncthreads();
    float Ar[16];
    #pragma unroll
    for (int n = 0; n < 16; ++n) Ar[n] = -__expf(alog[t * 16 + n]) * LOG2E;
    float dtr[32], ur[32];
    #pragma unroll
    for (int i = 0; i < 32; ++i) dtr[i] = delta[(rb + i) * DH + t];
    #pragma unroll
    for (int i = 0; i < 32; ++i) ur[i] = xf[(rb + i) * DH + t];
    float h[16], p[16];
    #pragma unroll
    for (int n = 0; n < 16; ++n) { h[n] = 0.f; p[n] = 1.f; }
    for (int i = 0; i < CH1; ++i) {
        float dt = dtr[i];
        float du = dt * ur[i];
        float bl[16];
        *(f32x4*)&bl[0]  = *(const f32x4*)&b_s[i * 16];
        *(f32x4*)&bl[4]  = *(const f32x4*)&b_s[i * 16 + 4];
        *(f32x4*)&bl[8]  = *(const f32x4*)&b_s[i * 16 + 8];
        *(f32x4*)&bl[12] = *(const f32x4*)&b_s[i * 16 + 12];
        #pragma unroll
        for (int n = 0; n < 16; ++n) {
            float a = exp2f(dt * Ar[n]);
            h[n] = fmaf(a, h[n], du * bl[n]);
            p[n] *= a;
        }
    }
    size_t qb = (((size_t)sb * NCH + ch) * 4) * 512 + (size_t)t * 4;
    #pragma unroll
    for (int n4 = 0; n4 < 4; ++n4) {
        f32x4 pv = { p[n4 * 4], p[n4 * 4 + 1], p[n4 * 4 + 2], p[n4 * 4 + 3] };
        f32x4 hv = { h[n4 * 4], h[n4 * 4 + 1], h[n4 * 4 + 2], h[n4 * 4 + 3] };
        *(f32x4*)&P[qb + (size_t)n4 * 512] = pv;
        *(f32x4*)&H[qb + (size_t)n4 * 512] = hv;
    }
}

__global__ __launch_bounds__(256) void scan_p2(const float* __restrict__ P, float* __restrict__ H)
{
    __shared__ float Ps[NCH * 16], Hs[NCH * 16];
    int t = threadIdx.x;
    int d = blockIdx.x, sb = blockIdx.y;
    for (int q = t; q < 512; q += 256) {
        int ch = q >> 2, n4 = q & 3;
        size_t g = (((size_t)sb * NCH + ch) * 4 + n4) * 512 + (size_t)d * 4;
        *(f32x4*)&Ps[ch * 16 + n4 * 4] = *(const f32x4*)&P[g];
        *(f32x4*)&Hs[ch * 16 + n4 * 4] = *(const f32x4*)&H[g];
    }
    __syncthreads();
    if (t < 16) {
        float hin = 0.f;
        for (int c = 0; c < NCH; ++c) {
            float pp = Ps[c * 16 + t], hl = Hs[c * 16 + t];
            Hs[c * 16 + t] = hin;
            hin = fmaf(pp, hin, hl);
        }
    }
    __syncthreads();
    for (int q = t; q < 512; q += 256) {
        int ch = q >> 2, n4 = q & 3;
        size_t g = (((size_t)sb * NCH + ch) * 4 + n4) * 512 + (size_t)d * 4;
        *(f32x4*)&H[g] = *(const f32x4*)&Hs[ch * 16 + n4 * 4];
    }
}

// phase 3: replay with h_init; dt AND u register-prefetched; coalesced H reads
__global__ __launch_bounds__(128) void scan_p3(
    const float* __restrict__ delta, const float* __restrict__ xf,
    const float* __restrict__ BC, const float* __restrict__ alog,
    const float* __restrict__ Dp, const float* __restrict__ H,
    unsigned short* __restrict__ catb)
{
    __shared__ float b_s[CH1 * 16];
    __shared__ float c_s[CH1 * 16];
    int t = threadIdx.x;
    int ch = blockIdx.x, sb = blockIdx.y;
    size_t rb = (size_t)sb * LL + (size_t)ch * CH1;
    {
        int row = t >> 2, c4 = (t & 3) * 4;
        *(f32x4*)&b_s[row * 16 + c4] = *(const f32x4*)&BC[(rb + row) * 32 + c4];
        *(f32x4*)&c_s[row * 16 + c4] = *(const f32x4*)&BC[(rb + row) * 32 + 16 + c4];
    }
    __syncthreads();
    float Ar[16];
    #pragma unroll
    for (int n = 0; n < 16; ++n) Ar[n] = -__expf(alog[t * 16 + n]) * LOG2E;
    float Dv = Dp[t];
    float dtr[32], ur[32];
    #pragma unroll
    for (int i = 0; i < 32; ++i) dtr[i] = delta[(rb + i) * DH + t];
    #pragma unroll
    for (int i = 0; i < 32; ++i) ur[i] = xf[(rb + i) * DH + t];
    size_t qb = (((size_t)sb * NCH + ch) * 4) * 512 + (size_t)t * 4;
    float h[16];
    #pragma unroll
    for (int n4 = 0; n4 < 4; ++n4) {
        f32x4 hv = *(const f32x4*)&H[qb + (size_t)n4 * 512];
        h[n4 * 4] = hv.x; h[n4 * 4 + 1] = hv.y; h[n4 * 4 + 2] = hv.z; h[n4 * 4 + 3] = hv.w;
    }
    for (int i = 0; i < CH1; ++i) {
        float dt = dtr[i];
        float uu = ur[i];
        float du = dt * uu;
        float bl[16], cl[16];
        *(f32x4*)&bl[0]  = *(const f32x4*)&b_s[i * 16];
        *(f32x4*)&bl[4]  = *(const f32x4*)&b_s[i * 16 + 4];
        *(f32x4*)&bl[8]  = *(const f32x4*)&b_s[i * 16 + 8];
        *(f32x4*)&bl[12] = *(const f32x4*)&b_s[i * 16 + 12];
        *(f32x4*)&cl[0]  = *(const f32x4*)&c_s[i * 16];
        *(f32x4*)&cl[4]  = *(const f32x4*)&c_s[i * 16 + 4];
        *(f32x4*)&cl[8]  = *(const f32x4*)&c_s[i * 16 + 8];
        *(f32x4*)&cl[12] = *(const f32x4*)&c_s[i * 16 + 12];
        float y0 = uu * Dv, y1 = 0.f, y2 = 0.f, y3 = 0.f;
        #pragma unroll
        for (int n = 0; n < 16; n += 4) {
            float a0 = exp2f(dt * Ar[n]);
            float a1 = exp2f(dt * Ar[n + 1]);
            float a2 = exp2f(dt * Ar[n + 2]);
            float a3 = exp2f(dt * Ar[n + 3]);
            h[n]     = fmaf(a0, h[n],     du * bl[n]);
            h[n + 1] = fmaf(a1, h[n + 1], du * bl[n + 1]);
            h[n + 2] = fmaf(a2, h[n + 2], du * bl[n + 2]);
            h[n + 3] = fmaf(a3, h[n + 3], du * bl[n + 3]);
            y0 = fmaf(h[n],     cl[n],     y0);
            y1 = fmaf(h[n + 1], cl[n + 1], y1);
            y2 = fmaf(h[n + 2], cl[n + 2], y2);
            y3 = fmaf(h[n + 3], cl[n + 3], y3);
        }
        float y = (y0 + y1) + (y2 + y3);
        catb[(rb + i) * DM + t] = f2bf(y);
    }
}

extern "C" void kernel_launch(void* const* d_in, const int* in_sizes, int n_in,
                              void* d_out, int out_size, void* d_ws, size_t ws_size,
                              hipStream_t stream) {
    const float* u0   = (const float*)d_in[0];
    const float* u1   = (const float*)d_in[1];
    const float* inw  = (const float*)d_in[2];
    const float* cxw  = (const float*)d_in[3];
    const float* czw  = (const float*)d_in[4];
    const float* xpw  = (const float*)d_in[5];
    const float* dtw  = (const float*)d_in[6];
    const float* dtb  = (const float*)d_in[7];
    const float* alog = (const float*)d_in[8];
    const float* Dp   = (const float*)d_in[9];
    const float* outw = (const float*)d_in[10];

    // Layout (same as R6-R9):
    //   [0 : 16.8M]      ubf (prep->gemm1), then delta (convproj..scan_p3)
    //   [16.8M : 33.6M]  xzbf (gemm1->convproj)   [fallback: then P/H]
    //   [33.6M : 50.3M]  xf f32
    //   [50.3M : 54.5M]  BC
    //   [54.5M : 71.3M]  catb
    //   [71.3M : 71.6M]  wbi, wbo, Wb
    //   fused path: P/H fresh at [71.6M : 88.4M]
    char* ws = (char*)d_ws;
    unsigned short* ubf  = (unsigned short*)(ws + 0);
    float* delta         = (float*)(ws + 0);
    unsigned short* xzbf = (unsigned short*)(ws + 16777216);
    float* P_a           = (float*)(ws + 16777216);
    float* H_a           = (float*)(ws + 25165824);
    float* xf            = (float*)(ws + 33554432);
    float* BC            = (float*)(ws + 50331648);
    unsigned short* catb = (unsigned short*)(ws + 54525952);
    unsigned short* wbi  = (unsigned short*)(ws + 71303168);
    unsigned short* wbo  = (unsigned short*)(ws + 71434240);
    unsigned short* Wb   = (unsigned short*)(ws + 71565312);
    float* P_f           = (float*)(ws + 71606272);
    float* H_f           = (float*)(ws + 79994880);

    float* outp = (float*)d_out;

    prep_kernel<<<8340, 256, 0, stream>>>(u0, u1, inw, outw, xpw, dtw, ubf, wbi, wbo, Wb);
    gemm_bt<0><<<dim3(256, 2), 256, 0, stream>>>(ubf, wbi, nullptr, xzbf);

    if (ws_size >= 88383488ull) {
        convproj_k<1><<<1024, 256, 0, stream>>>(xzbf, Wb, cxw, czw, dtb, alog,
                                                xf, catb, delta, BC, P_f, H_f);
        scan_p2<<<dim3(128, 8), 256, 0, stream>>>(P_f, H_f);
        scan_p3<<<dim3(NCH, 8), 128, 0, stream>>>(delta, xf, BC, alog, Dp, H_f, catb);
    } else {
        convproj_k<0><<<1024, 256, 0, stream>>>(xzbf, Wb, cxw, czw, dtb, alog,
                                                xf, catb, delta, BC, nullptr, nullptr);
        scan_p1<<<dim3(NCH, 8), 128, 0, stream>>>(delta, xf, BC, alog, P_a, H_a);
        scan_p2<<<dim3(128, 8), 256, 0, stream>>>(P_a, H_a);
        scan_p3<<<dim3(NCH, 8), 128, 0, stream>>>(delta, xf, BC, alog, Dp, H_a, catb);
    }
    gemm_bt<1><<<dim3(256, 2), 256, 0, stream>>>(catb, wbo, outp, nullptr);
}

// Round 12
// 212.999 us; speedup vs baseline: 1.0734x; 1.0734x over previous
//
#include <hip/hip_runtime.h>
#include <hip/hip_bf16.h>
#include <cstdint>

#define DEV __device__ __forceinline__

typedef __attribute__((ext_vector_type(8))) short short8;
typedef __attribute__((ext_vector_type(4))) float f32x4;
typedef __attribute__((ext_vector_type(4))) unsigned short us4;
typedef __attribute__((ext_vector_type(8))) unsigned short us8;

DEV unsigned short f2bf(float x) {
    unsigned int u = __float_as_uint(x);
    unsigned int r = (u + 0x7FFFu + ((u >> 16) & 1u)) >> 16;
    return (unsigned short)r;
}
DEV float bf2f(unsigned short h) { return __uint_as_float(((unsigned int)h) << 16); }

// async global->LDS, 16B per lane; LDS dest is wave-uniform base + lane*16 (HW rule)
DEV void gld_lds16(const unsigned short* g, unsigned short* l) {
    __builtin_amdgcn_global_load_lds(
        (const __attribute__((address_space(1))) unsigned int*)g,
        (__attribute__((address_space(3))) unsigned int*)l, 16, 0, 0);
}

// SiLU with fast division (v_rcp_f32 path; error below bf16 rounding)
DEV float silu(float v) {
    return __fdividef(v, 1.f + __expf(-v));
}

// problem sizes
#define LL 4096
#define DM 256
#define DH 128
#define SB_TOT 8       // 2 streams * 4 batch
#define CH1 32         // scan chunk length
#define NCH 128        // LL / CH1
#define LOG2E 1.44269504088896f

// ---------------- prep: fp32 -> bf16 (u, in_proj, out_proj) + fused proj weight Wb ----------------
__global__ __launch_bounds__(256) void prep_kernel(
    const float* __restrict__ u0, const float* __restrict__ u1,
    const float* __restrict__ inw, const float* __restrict__ outw,
    const float* __restrict__ xpw, const float* __restrict__ dtw,
    unsigned short* __restrict__ ubf, unsigned short* __restrict__ wbi,
    unsigned short* __restrict__ wbo, unsigned short* __restrict__ Wb)
{
    int gid = blockIdx.x * 256 + threadIdx.x;
    int i = gid * 4;
    if (i < 4194304) {
        f32x4 v = *(const f32x4*)&u0[i];
        us4 r = { f2bf(v.x), f2bf(v.y), f2bf(v.z), f2bf(v.w) };
        *(us4*)&ubf[i] = r;
    } else if (i < 8388608) {
        int j = i - 4194304;
        f32x4 v = *(const f32x4*)&u1[j];
        us4 r = { f2bf(v.x), f2bf(v.y), f2bf(v.z), f2bf(v.w) };
        *(us4*)&ubf[4194304 + j] = r;
    } else if (i < 8454144) {
        int j = i - 8388608;
        f32x4 v = *(const f32x4*)&inw[j];
        us4 r = { f2bf(v.x), f2bf(v.y), f2bf(v.z), f2bf(v.w) };
        *(us4*)&wbi[j] = r;
    } else if (i < 8519680) {
        int j = i - 8454144;
        f32x4 v = *(const f32x4*)&outw[j];
        us4 r = { f2bf(v.x), f2bf(v.y), f2bf(v.z), f2bf(v.w) };
        *(us4*)&wbo[j] = r;
    } else if (i < 8540160) {
        int j = i - 8519680;            // 0..20476, step 4
        int n = j >> 7, k0 = j & 127;
        if (n < 128) {
            float a0 = 0.f, a1 = 0.f, a2 = 0.f, a3 = 0.f;
            const float* dw = dtw + n * 16;
            #pragma unroll
            for (int r = 0; r < 16; ++r) {
                float w = dw[r];
                const float* xr = xpw + r * 128 + k0;
                a0 = fmaf(w, xr[0], a0);
                a1 = fmaf(w, xr[1], a1);
                a2 = fmaf(w, xr[2], a2);
                a3 = fmaf(w, xr[3], a3);
            }
            us4 rr = { f2bf(a0), f2bf(a1), f2bf(a2), f2bf(a3) };
            *(us4*)&Wb[n * 128 + k0] = rr;
        } else {
            f32x4 v = *(const f32x4*)&xpw[(n - 112) * 128 + k0];
            us4 rr = { f2bf(v.x), f2bf(v.y), f2bf(v.z), f2bf(v.w) };
            *(us4*)&Wb[n * 128 + k0] = rr;
        }
    }
}

// ---------------- bf16 MFMA GEMM (m97 structure): C[M,N] = A[M,K] * B[N,K]^T, K=N=256 ----------------
template<int F32OUT>
__global__ __launch_bounds__(256) void gemm_bt(
    const unsigned short* __restrict__ A, const unsigned short* __restrict__ B,
    float* __restrict__ Cf, unsigned short* __restrict__ Cb)
{
    __shared__ __align__(16) unsigned short As[128 * 32];
    __shared__ __align__(16) unsigned short Bs[128 * 32];
    const int t = threadIdx.x;
    const int m0 = blockIdx.x * 128, n0 = blockIdx.y * 128;
    const int lane = t & 63, wv = t >> 6;
    const int wm = (wv & 1) * 64, wn = (wv >> 1) * 64;
    const int lr = lane & 15, lk = (lane >> 4) * 8;
    const int srow = lane >> 2, scol = (lane & 3) * 8;

    f32x4 acc[4][4] = {};
    for (int kt = 0; kt < 8; ++kt) {
        const int k0 = kt * 32;
        #pragma unroll
        for (int h = 0; h < 2; ++h) {
            const int c = wv + h * 4;
            const unsigned short* ga = A + (size_t)(m0 + c * 16 + srow) * 256 + k0 + scol;
            const unsigned short* gb = B + (size_t)(n0 + c * 16 + srow) * 256 + k0 + scol;
            gld_lds16(ga, &As[c * 512]);
            gld_lds16(gb, &Bs[c * 512]);
        }
        __syncthreads();
        short8 av[4], bv[4];
        #pragma unroll
        for (int i = 0; i < 4; ++i) av[i] = *(const short8*)&As[(wm + i * 16 + lr) * 32 + lk];
        #pragma unroll
        for (int i = 0; i < 4; ++i) bv[i] = *(const short8*)&Bs[(wn + i * 16 + lr) * 32 + lk];
        #pragma unroll
        for (int i = 0; i < 4; ++i)
            #pragma unroll
            for (int j = 0; j < 4; ++j)
                acc[i][j] = __builtin_amdgcn_mfma_f32_16x16x32_bf16(av[i], bv[j], acc[i][j], 0, 0, 0);
        __syncthreads();
    }
    #pragma unroll
    for (int i = 0; i < 4; ++i) {
        #pragma unroll
        for (int j = 0; j < 4; ++j) {
            int r0 = m0 + wm + i * 16 + (lane >> 4) * 4;
            int cc = n0 + wn + j * 16 + lr;
            #pragma unroll
            for (int r = 0; r < 4; ++r) {
                float v = acc[i][j][r];
                if (F32OUT) Cf[(size_t)(r0 + r) * 256 + cc] = v;
                else        Cb[(size_t)(r0 + r) * 256 + cc] = f2bf(v);
            }
        }
    }
}

// ---------------- fused depthwise conv + SiLU + proj MFMA + softplus + scan-p1 ----------------
// BM=32, grid 1024. Conv weights hoisted (loop-invariant). Scan tail all-LDS.
template<int FUSE_SCAN>
__global__ __launch_bounds__(256) void convproj_k(
    const unsigned short* __restrict__ xz, const unsigned short* __restrict__ Wb,
    const float* __restrict__ wx, const float* __restrict__ wz,
    const float* __restrict__ dtb, const float* __restrict__ alog,
    float* __restrict__ xf, unsigned short* __restrict__ catb,
    float* __restrict__ delta, float* __restrict__ BC,
    float* __restrict__ P, float* __restrict__ H)
{
    // smem: [0:16896) union{ As[32][136] bf16 (8704B) | dl_s[32][132] f32 }
    //       [16896:33792) xf_s[32][132] f32 ; [33792:35840) bc_s[32][16] f32
    __shared__ __align__(16) char smem[35840];
    unsigned short* As = (unsigned short*)smem;
    float* dl_s = (float*)smem;
    float* xf_s = (float*)(smem + 16896);
    float* bc_s = (float*)(smem + 33792);
    const int t = threadIdx.x;
    // bijective XCD-aligned mapping (rows this block reads were produced on its XCD)
    const int kk = blockIdx.x & 7, yy = blockIdx.x >> 3;
    const int m0 = (4 * kk + (yy & 3) + 32 * (yy >> 2)) * 32;

    // conv: g,c invariant across the 4 row-iterations -> hoist weight loads
    const int gg = t & 31;
    const bool isx = gg < 16;
    const int c = (isx ? gg : gg - 16) * 8;
    const float* wp = isx ? wx : wz;
    float wreg[24];
    #pragma unroll
    for (int j = 0; j < 6; ++j) *(f32x4*)&wreg[j * 4] = *(const f32x4*)(wp + c * 3 + j * 4);
    #pragma unroll
    for (int i = 0; i < 4; ++i) {
        int r = (t >> 5) + i * 8;
        int gr = m0 + r;
        int l = gr & 4095;
        const unsigned short* bp = xz + (size_t)gr * 256 + (isx ? c : 128 + c);
        us8 zz = (us8)0;
        us8 vm = (l > 0)    ? *(const us8*)(bp - 256) : zz;
        us8 v0 = *(const us8*)bp;
        us8 vp = (l < 4095) ? *(const us8*)(bp + 256) : zz;
        float o[8];
        #pragma unroll
        for (int j = 0; j < 8; ++j) {
            float v = bf2f(vm[j]) * wreg[j * 3] + bf2f(v0[j]) * wreg[j * 3 + 1]
                    + bf2f(vp[j]) * wreg[j * 3 + 2];
            o[j] = silu(v);
        }
        us8 rb8 = { f2bf(o[0]), f2bf(o[1]), f2bf(o[2]), f2bf(o[3]),
                    f2bf(o[4]), f2bf(o[5]), f2bf(o[6]), f2bf(o[7]) };
        if (isx) {
            *(us8*)&As[r * 136 + c] = rb8;
            *(f32x4*)&xf_s[r * 132 + c]     = *(f32x4*)&o[0];
            *(f32x4*)&xf_s[r * 132 + c + 4] = *(f32x4*)&o[4];
            *(f32x4*)&xf[(size_t)gr * 128 + c]     = *(f32x4*)&o[0];
            *(f32x4*)&xf[(size_t)gr * 128 + c + 4] = *(f32x4*)&o[4];
        } else {
            *(us8*)&catb[(size_t)gr * 256 + 128 + c] = rb8;
        }
    }
    __syncthreads();
    const int lane = t & 63, wv = t >> 6;
    const int lr = lane & 15, lk = (lane >> 4) * 8;
    const int rt = (wv & 1) * 16;        // row tile base
    const int jbase = (wv >> 1) * 5;     // col-tile base (0 or 5)
    f32x4 acc[5] = {};
    #pragma unroll
    for (int kt = 0; kt < 4; ++kt) {
        const int k0 = kt * 32;
        short8 av = *(const short8*)&As[(rt + lr) * 136 + k0 + lk];
        #pragma unroll
        for (int j = 0; j < 5; ++j) {
            short8 bv = *(const short8*)(Wb + ((jbase + j) * 16 + lr) * 128 + k0 + lk);
            acc[j] = __builtin_amdgcn_mfma_f32_16x16x32_bf16(av, bv, acc[j], 0, 0, 0);
        }
    }
    __syncthreads();   // As dead -> dl_s may overlay it
    const int r0 = (lane >> 4) * 4;
    #pragma unroll
    for (int j = 0; j < 5; ++j) {
        int jj = jbase + j;
        int col = jj * 16 + lr;
        #pragma unroll
        for (int r = 0; r < 4; ++r) {
            float v = acc[j][r];
            int lrow = rt + r0 + r;
            size_t row = (size_t)m0 + lrow;
            if (jj < 8) {
                float x = v + dtb[col];
                float sp = (x > 20.f) ? x : __logf(1.f + __expf(x));
                delta[row * 128 + col] = sp;
                if (FUSE_SCAN) dl_s[lrow * 132 + col] = sp;
            } else {
                BC[row * 32 + (col - 128)] = v;
                if (FUSE_SCAN && jj == 8) bc_s[lrow * 16 + lr] = v;   // B rows for scan
            }
        }
    }
    if (!FUSE_SCAN) return;

    // ---- scan phase-1 for this block's chunk; n split across thread halves; all-LDS reads ----
    __syncthreads();
    const int hh = t >> 7, tl = t & 127;
    const int sb = m0 >> 12;
    const int ch = (m0 & 4095) >> 5;
    float Ar[8];
    #pragma unroll
    for (int n = 0; n < 8; ++n) Ar[n] = -__expf(alog[tl * 16 + hh * 8 + n]) * LOG2E;
    float h[8], p[8];
    #pragma unroll
    for (int n = 0; n < 8; ++n) { h[n] = 0.f; p[n] = 1.f; }
    #pragma unroll 4
    for (int i = 0; i < CH1; ++i) {
        float dt = dl_s[i * 132 + tl];
        float du = dt * xf_s[i * 132 + tl];
        float bl[8];
        *(f32x4*)&bl[0] = *(const f32x4*)&bc_s[i * 16 + hh * 8];
        *(f32x4*)&bl[4] = *(const f32x4*)&bc_s[i * 16 + hh * 8 + 4];
        #pragma unroll
        for (int n = 0; n < 8; ++n) {
            float a = exp2f(dt * Ar[n]);
            h[n] = fmaf(a, h[n], du * bl[n]);
            p[n] *= a;
        }
    }
    size_t ob = (((size_t)sb * NCH + ch) * 128 + tl) * 16 + hh * 8;
    f32x4 pv0 = { p[0], p[1], p[2], p[3] };
    f32x4 pv1 = { p[4], p[5], p[6], p[7] };
    f32x4 hv0 = { h[0], h[1], h[2], h[3] };
    f32x4 hv1 = { h[4], h[5], h[6], h[7] };
    *(f32x4*)&P[ob]     = pv0;
    *(f32x4*)&P[ob + 4] = pv1;
    *(f32x4*)&H[ob]     = hv0;
    *(f32x4*)&H[ob + 4] = hv1;
}

// ---------------- selective scan, chunked 3-phase (standalone p1 = fallback) ----------------
__global__ __launch_bounds__(128) void scan_p1(
    const float* __restrict__ delta, const float* __restrict__ xf,
    const float* __restrict__ BC, const float* __restrict__ alog,
    float* __restrict__ P, float* __restrict__ H)
{
    __shared__ float b_s[CH1 * 16];
    int t = threadIdx.x;                 // d channel
    int ch = blockIdx.x, sb = blockIdx.y;
    size_t rb = (size_t)sb * LL + (size_t)ch * CH1;
    {
        int row = t >> 2, c4 = (t & 3) * 4;
        *(f32x4*)&b_s[row * 16 + c4] = *(const f32x4*)&BC[(rb + row) * 32 + c4];
    }
    __syncthreads();
    float Ar[16];
    #pragma unroll
    for (int n = 0; n < 16; ++n) Ar[n] = -__expf(alog[t * 16 + n]) * LOG2E;
    float dtr[32], ur[32];
    #pragma unroll
    for (int i = 0; i < 32; ++i) dtr[i] = delta[(rb + i) * DH + t];
    #pragma unroll
    for (int i = 0; i < 32; ++i) ur[i] = xf[(rb + i) * DH + t];
    float h[16], p[16];
    #pragma unroll
    for (int n = 0; n < 16; ++n) { h[n] = 0.f; p[n] = 1.f; }
    for (int i = 0; i < CH1; ++i) {
        float dt = dtr[i];
        float du = dt * ur[i];
        float bl[16];
        *(f32x4*)&bl[0]  = *(const f32x4*)&b_s[i * 16];
        *(f32x4*)&bl[4]  = *(const f32x4*)&b_s[i * 16 + 4];
        *(f32x4*)&bl[8]  = *(const f32x4*)&b_s[i * 16 + 8];
        *(f32x4*)&bl[12] = *(const f32x4*)&b_s[i * 16 + 12];
        #pragma unroll
        for (int n = 0; n < 16; ++n) {
            float a = exp2f(dt * Ar[n]);
            h[n] = fmaf(a, h[n], du * bl[n]);
            p[n] *= a;
        }
    }
    size_t ob = (((size_t)sb * NCH + ch) * 128 + t) * 16;
    #pragma unroll
    for (int n4 = 0; n4 < 16; n4 += 4) {
        f32x4 pv = { p[n4], p[n4 + 1], p[n4 + 2], p[n4 + 3] };
        f32x4 hv = { h[n4], h[n4 + 1], h[n4 + 2], h[n4 + 3] };
        *(f32x4*)&P[ob + n4] = pv;
        *(f32x4*)&H[ob + n4] = hv;
    }
}

__global__ __launch_bounds__(256) void scan_p2(const float* __restrict__ P, float* __restrict__ H)
{
    __shared__ float Ps[NCH * 16], Hs[NCH * 16];
    int t = threadIdx.x;
    int d = blockIdx.x, sb = blockIdx.y;
    for (int q = t; q < NCH * 4; q += 256) {
        int ch = q >> 2, c4 = (q & 3) * 4;
        size_t g = (((size_t)sb * NCH + ch) * 128 + d) * 16 + c4;
        *(f32x4*)&Ps[ch * 16 + c4] = *(const f32x4*)&P[g];
        *(f32x4*)&Hs[ch * 16 + c4] = *(const f32x4*)&H[g];
    }
    __syncthreads();
    if (t < 16) {
        float hin = 0.f;
        for (int c = 0; c < NCH; ++c) {
            float pp = Ps[c * 16 + t], hl = Hs[c * 16 + t];
            Hs[c * 16 + t] = hin;
            hin = fmaf(pp, hin, hl);
        }
    }
    __syncthreads();
    for (int q = t; q < NCH * 4; q += 256) {
        int ch = q >> 2, c4 = (q & 3) * 4;
        size_t g = (((size_t)sb * NCH + ch) * 128 + d) * 16 + c4;
        *(f32x4*)&H[g] = *(const f32x4*)&Hs[ch * 16 + c4];
    }
}

// phase 3: replay with h_init; dt AND u register-prefetched before the serial loop
__global__ __launch_bounds__(128) void scan_p3(
    const float* __restrict__ delta, const float* __restrict__ xf,
    const float* __restrict__ BC, const float* __restrict__ alog,
    const float* __restrict__ Dp, const float* __restrict__ H,
    unsigned short* __restrict__ catb)
{
    __shared__ float b_s[CH1 * 16];
    __shared__ float c_s[CH1 * 16];
    int t = threadIdx.x;
    int ch = blockIdx.x, sb = blockIdx.y;
    size_t rb = (size_t)sb * LL + (size_t)ch * CH1;
    {
        int row = t >> 2, c4 = (t & 3) * 4;
        *(f32x4*)&b_s[row * 16 + c4] = *(const f32x4*)&BC[(rb + row) * 32 + c4];
        *(f32x4*)&c_s[row * 16 + c4] = *(const f32x4*)&BC[(rb + row) * 32 + 16 + c4];
    }
    __syncthreads();
    float Ar[16];
    #pragma unroll
    for (int n = 0; n < 16; ++n) Ar[n] = -__expf(alog[t * 16 + n]) * LOG2E;
    float Dv = Dp[t];
    float dtr[32], ur[32];
    #pragma unroll
    for (int i = 0; i < 32; ++i) dtr[i] = delta[(rb + i) * DH + t];
    #pragma unroll
    for (int i = 0; i < 32; ++i) ur[i] = xf[(rb + i) * DH + t];
    size_t ob = (((size_t)sb * NCH + ch) * 128 + t) * 16;
    float h[16];
    #pragma unroll
    for (int n4 = 0; n4 < 16; n4 += 4) {
        f32x4 hv = *(const f32x4*)&H[ob + n4];
        h[n4] = hv.x; h[n4 + 1] = hv.y; h[n4 + 2] = hv.z; h[n4 + 3] = hv.w;
    }
    for (int i = 0; i < CH1; ++i) {
        float dt = dtr[i];
        float uu = ur[i];
        float du = dt * uu;
        float bl[16], cl[16];
        *(f32x4*)&bl[0]  = *(const f32x4*)&b_s[i * 16];
        *(f32x4*)&bl[4]  = *(const f32x4*)&b_s[i * 16 + 4];
        *(f32x4*)&bl[8]  = *(const f32x4*)&b_s[i * 16 + 8];
        *(f32x4*)&bl[12] = *(const f32x4*)&b_s[i * 16 + 12];
        *(f32x4*)&cl[0]  = *(const f32x4*)&c_s[i * 16];
        *(f32x4*)&cl[4]  = *(const f32x4*)&c_s[i * 16 + 4];
        *(f32x4*)&cl[8]  = *(const f32x4*)&c_s[i * 16 + 8];
        *(f32x4*)&cl[12] = *(const f32x4*)&c_s[i * 16 + 12];
        float y0 = uu * Dv, y1 = 0.f, y2 = 0.f, y3 = 0.f;
        #pragma unroll
        for (int n = 0; n < 16; n += 4) {
            float a0 = exp2f(dt * Ar[n]);
            float a1 = exp2f(dt * Ar[n + 1]);
            float a2 = exp2f(dt * Ar[n + 2]);
            float a3 = exp2f(dt * Ar[n + 3]);
            h[n]     = fmaf(a0, h[n],     du * bl[n]);
            h[n + 1] = fmaf(a1, h[n + 1], du * bl[n + 1]);
            h[n + 2] = fmaf(a2, h[n + 2], du * bl[n + 2]);
            h[n + 3] = fmaf(a3, h[n + 3], du * bl[n + 3]);
            y0 = fmaf(h[n],     cl[n],     y0);
            y1 = fmaf(h[n + 1], cl[n + 1], y1);
            y2 = fmaf(h[n + 2], cl[n + 2], y2);
            y3 = fmaf(h[n + 3], cl[n + 3], y3);
        }
        float y = (y0 + y1) + (y2 + y3);
        catb[(rb + i) * DM + t] = f2bf(y);
    }
}

extern "C" void kernel_launch(void* const* d_in, const int* in_sizes, int n_in,
                              void* d_out, int out_size, void* d_ws, size_t ws_size,
                              hipStream_t stream) {
    const float* u0   = (const float*)d_in[0];
    const float* u1   = (const float*)d_in[1];
    const float* inw  = (const float*)d_in[2];
    const float* cxw  = (const float*)d_in[3];
    const float* czw  = (const float*)d_in[4];
    const float* xpw  = (const float*)d_in[5];
    const float* dtw  = (const float*)d_in[6];
    const float* dtb  = (const float*)d_in[7];
    const float* alog = (const float*)d_in[8];
    const float* Dp   = (const float*)d_in[9];
    const float* outw = (const float*)d_in[10];

    // Layout (same as R6-R9):
    //   [0 : 16.8M]      ubf (prep->gemm1), then delta (convproj..scan_p3)
    //   [16.8M : 33.6M]  xzbf (gemm1->convproj)   [fallback: then P/H]
    //   [33.6M : 50.3M]  xf f32
    //   [50.3M : 54.5M]  BC
    //   [54.5M : 71.3M]  catb
    //   [71.3M : 71.6M]  wbi, wbo, Wb
    //   fused path: P/H fresh at [71.6M : 88.4M]
    char* ws = (char*)d_ws;
    unsigned short* ubf  = (unsigned short*)(ws + 0);
    float* delta         = (float*)(ws + 0);
    unsigned short* xzbf = (unsigned short*)(ws + 16777216);
    float* P_a           = (float*)(ws + 16777216);
    float* H_a           = (float*)(ws + 25165824);
    float* xf            = (float*)(ws + 33554432);
    float* BC            = (float*)(ws + 50331648);
    unsigned short* catb = (unsigned short*)(ws + 54525952);
    unsigned short* wbi  = (unsigned short*)(ws + 71303168);
    unsigned short* wbo  = (unsigned short*)(ws + 71434240);
    unsigned short* Wb   = (unsigned short*)(ws + 71565312);
    float* P_f           = (float*)(ws + 71606272);
    float* H_f           = (float*)(ws + 79994880);

    float* outp = (float*)d_out;

    prep_kernel<<<8340, 256, 0, stream>>>(u0, u1, inw, outw, xpw, dtw, ubf, wbi, wbo, Wb);
    gemm_bt<0><<<dim3(256, 2), 256, 0, stream>>>(ubf, wbi, nullptr, xzbf);

    if (ws_size >= 88383488ull) {
        convproj_k<1><<<1024, 256, 0, stream>>>(xzbf, Wb, cxw, czw, dtb, alog,
                                                xf, catb, delta, BC, P_f, H_f);
        scan_p2<<<dim3(128, 8), 256, 0, stream>>>(P_f, H_f);
        scan_p3<<<dim3(NCH, 8), 128, 0, stream>>>(delta, xf, BC, alog, Dp, H_f, catb);
    } else {
        convproj_k<0><<<1024, 256, 0, stream>>>(xzbf, Wb, cxw, czw, dtb, alog,
                                                xf, catb, delta, BC, nullptr, nullptr);
        scan_p1<<<dim3(NCH, 8), 128, 0, stream>>>(delta, xf, BC, alog, P_a, H_a);
        scan_p2<<<dim3(128, 8), 256, 0, stream>>>(P_a, H_a);
        scan_p3<<<dim3(NCH, 8), 128, 0, stream>>>(delta, xf, BC, alog, Dp, H_a, catb);
    }
    gemm_bt<1><<<dim3(256, 2), 256, 0, stream>>>(catb, wbo, outp, nullptr);
}

// Round 13
// 212.475 us; speedup vs baseline: 1.0761x; 1.0025x over previous
//
#include <hip/hip_runtime.h>
#include <hip/hip_bf16.h>
#include <cstdint>

#define DEV __device__ __forceinline__

typedef __attribute__((ext_vector_type(8))) short short8;
typedef __attribute__((ext_vector_type(4))) float f32x4;
typedef __attribute__((ext_vector_type(4))) unsigned short us4;
typedef __attribute__((ext_vector_type(8))) unsigned short us8;

DEV unsigned short f2bf(float x) {
    unsigned int u = __float_as_uint(x);
    unsigned int r = (u + 0x7FFFu + ((u >> 16) & 1u)) >> 16;
    return (unsigned short)r;
}
DEV float bf2f(unsigned short h) { return __uint_as_float(((unsigned int)h) << 16); }

// async global->LDS, 16B per lane; LDS dest is wave-uniform base + lane*16 (HW rule)
DEV void gld_lds16(const unsigned short* g, unsigned short* l) {
    __builtin_amdgcn_global_load_lds(
        (const __attribute__((address_space(1))) unsigned int*)g,
        (__attribute__((address_space(3))) unsigned int*)l, 16, 0, 0);
}

// SiLU with fast division (v_rcp_f32 path; error below bf16 rounding)
DEV float silu(float v) {
    return __fdividef(v, 1.f + __expf(-v));
}

// LDS-only barrier: orders LDS ops across waves WITHOUT draining outstanding
// global stores (default __syncthreads emits s_waitcnt vmcnt(0) -> full HBM
// write round-trip at every barrier). Safe when all cross-wave deps at the
// barrier are through LDS; global stores are consumed only by later kernels
// (kernel-end release). sched_barrier(0) fences compiler reordering (rule #18).
DEV void lds_barrier() {
    __builtin_amdgcn_sched_barrier(0);
    asm volatile("s_waitcnt lgkmcnt(0)" ::: "memory");
    __builtin_amdgcn_s_barrier();
    __builtin_amdgcn_sched_barrier(0);
}

// problem sizes
#define LL 4096
#define DM 256
#define DH 128
#define SB_TOT 8       // 2 streams * 4 batch
#define CH1 32         // scan chunk length
#define NCH 128        // LL / CH1
#define LOG2E 1.44269504088896f

// ---------------- prep: fp32 -> bf16 (u, in_proj, out_proj) + fused proj weight Wb ----------------
__global__ __launch_bounds__(256) void prep_kernel(
    const float* __restrict__ u0, const float* __restrict__ u1,
    const float* __restrict__ inw, const float* __restrict__ outw,
    const float* __restrict__ xpw, const float* __restrict__ dtw,
    unsigned short* __restrict__ ubf, unsigned short* __restrict__ wbi,
    unsigned short* __restrict__ wbo, unsigned short* __restrict__ Wb)
{
    int gid = blockIdx.x * 256 + threadIdx.x;
    int i = gid * 4;
    if (i < 4194304) {
        f32x4 v = *(const f32x4*)&u0[i];
        us4 r = { f2bf(v.x), f2bf(v.y), f2bf(v.z), f2bf(v.w) };
        *(us4*)&ubf[i] = r;
    } else if (i < 8388608) {
        int j = i - 4194304;
        f32x4 v = *(const f32x4*)&u1[j];
        us4 r = { f2bf(v.x), f2bf(v.y), f2bf(v.z), f2bf(v.w) };
        *(us4*)&ubf[4194304 + j] = r;
    } else if (i < 8454144) {
        int j = i - 8388608;
        f32x4 v = *(const f32x4*)&inw[j];
        us4 r = { f2bf(v.x), f2bf(v.y), f2bf(v.z), f2bf(v.w) };
        *(us4*)&wbi[j] = r;
    } else if (i < 8519680) {
        int j = i - 8454144;
        f32x4 v = *(const f32x4*)&outw[j];
        us4 r = { f2bf(v.x), f2bf(v.y), f2bf(v.z), f2bf(v.w) };
        *(us4*)&wbo[j] = r;
    } else if (i < 8540160) {
        int j = i - 8519680;            // 0..20476, step 4
        int n = j >> 7, k0 = j & 127;
        if (n < 128) {
            float a0 = 0.f, a1 = 0.f, a2 = 0.f, a3 = 0.f;
            const float* dw = dtw + n * 16;
            #pragma unroll
            for (int r = 0; r < 16; ++r) {
                float w = dw[r];
                const float* xr = xpw + r * 128 + k0;
                a0 = fmaf(w, xr[0], a0);
                a1 = fmaf(w, xr[1], a1);
                a2 = fmaf(w, xr[2], a2);
                a3 = fmaf(w, xr[3], a3);
            }
            us4 rr = { f2bf(a0), f2bf(a1), f2bf(a2), f2bf(a3) };
            *(us4*)&Wb[n * 128 + k0] = rr;
        } else {
            f32x4 v = *(const f32x4*)&xpw[(n - 112) * 128 + k0];
            us4 rr = { f2bf(v.x), f2bf(v.y), f2bf(v.z), f2bf(v.w) };
            *(us4*)&Wb[n * 128 + k0] = rr;
        }
    }
}

// ---------------- bf16 MFMA GEMM (m97 structure): C[M,N] = A[M,K] * B[N,K]^T, K=N=256 ----------------
// keeps standard __syncthreads: global_load_lds genuinely requires vmcnt drain.
template<int F32OUT>
__global__ __launch_bounds__(256) void gemm_bt(
    const unsigned short* __restrict__ A, const unsigned short* __restrict__ B,
    float* __restrict__ Cf, unsigned short* __restrict__ Cb)
{
    __shared__ __align__(16) unsigned short As[128 * 32];
    __shared__ __align__(16) unsigned short Bs[128 * 32];
    const int t = threadIdx.x;
    const int m0 = blockIdx.x * 128, n0 = blockIdx.y * 128;
    const int lane = t & 63, wv = t >> 6;
    const int wm = (wv & 1) * 64, wn = (wv >> 1) * 64;
    const int lr = lane & 15, lk = (lane >> 4) * 8;
    const int srow = lane >> 2, scol = (lane & 3) * 8;

    f32x4 acc[4][4] = {};
    for (int kt = 0; kt < 8; ++kt) {
        const int k0 = kt * 32;
        #pragma unroll
        for (int h = 0; h < 2; ++h) {
            const int c = wv + h * 4;
            const unsigned short* ga = A + (size_t)(m0 + c * 16 + srow) * 256 + k0 + scol;
            const unsigned short* gb = B + (size_t)(n0 + c * 16 + srow) * 256 + k0 + scol;
            gld_lds16(ga, &As[c * 512]);
            gld_lds16(gb, &Bs[c * 512]);
        }
        __syncthreads();
        short8 av[4], bv[4];
        #pragma unroll
        for (int i = 0; i < 4; ++i) av[i] = *(const short8*)&As[(wm + i * 16 + lr) * 32 + lk];
        #pragma unroll
        for (int i = 0; i < 4; ++i) bv[i] = *(const short8*)&Bs[(wn + i * 16 + lr) * 32 + lk];
        #pragma unroll
        for (int i = 0; i < 4; ++i)
            #pragma unroll
            for (int j = 0; j < 4; ++j)
                acc[i][j] = __builtin_amdgcn_mfma_f32_16x16x32_bf16(av[i], bv[j], acc[i][j], 0, 0, 0);
        __syncthreads();
    }
    #pragma unroll
    for (int i = 0; i < 4; ++i) {
        #pragma unroll
        for (int j = 0; j < 4; ++j) {
            int r0 = m0 + wm + i * 16 + (lane >> 4) * 4;
            int cc = n0 + wn + j * 16 + lr;
            #pragma unroll
            for (int r = 0; r < 4; ++r) {
                float v = acc[i][j][r];
                if (F32OUT) Cf[(size_t)(r0 + r) * 256 + cc] = v;
                else        Cb[(size_t)(r0 + r) * 256 + cc] = f2bf(v);
            }
        }
    }
}

// ---------------- fused depthwise conv + SiLU + proj MFMA + softplus + scan-p1 ----------------
// BM=32, grid 1024. All barriers are LDS-only (global stores drain in background).
template<int FUSE_SCAN>
__global__ __launch_bounds__(256) void convproj_k(
    const unsigned short* __restrict__ xz, const unsigned short* __restrict__ Wb,
    const float* __restrict__ wx, const float* __restrict__ wz,
    const float* __restrict__ dtb, const float* __restrict__ alog,
    float* __restrict__ xf, unsigned short* __restrict__ catb,
    float* __restrict__ delta, float* __restrict__ BC,
    float* __restrict__ P, float* __restrict__ H)
{
    // smem: [0:16896) union{ As[32][136] bf16 (8704B) | dl_s[32][132] f32 }
    //       [16896:33792) xf_s[32][132] f32 ; [33792:35840) bc_s[32][16] f32
    __shared__ __align__(16) char smem[35840];
    unsigned short* As = (unsigned short*)smem;
    float* dl_s = (float*)smem;
    float* xf_s = (float*)(smem + 16896);
    float* bc_s = (float*)(smem + 33792);
    const int t = threadIdx.x;
    // bijective XCD-aligned mapping (rows this block reads were produced on its XCD)
    const int kk = blockIdx.x & 7, yy = blockIdx.x >> 3;
    const int m0 = (4 * kk + (yy & 3) + 32 * (yy >> 2)) * 32;

    // conv: g,c invariant across the 4 row-iterations -> hoist weight loads
    const int gg = t & 31;
    const bool isx = gg < 16;
    const int c = (isx ? gg : gg - 16) * 8;
    const float* wp = isx ? wx : wz;
    float wreg[24];
    #pragma unroll
    for (int j = 0; j < 6; ++j) *(f32x4*)&wreg[j * 4] = *(const f32x4*)(wp + c * 3 + j * 4);
    #pragma unroll
    for (int i = 0; i < 4; ++i) {
        int r = (t >> 5) + i * 8;
        int gr = m0 + r;
        int l = gr & 4095;
        const unsigned short* bp = xz + (size_t)gr * 256 + (isx ? c : 128 + c);
        us8 zz = (us8)0;
        us8 vm = (l > 0)    ? *(const us8*)(bp - 256) : zz;
        us8 v0 = *(const us8*)bp;
        us8 vp = (l < 4095) ? *(const us8*)(bp + 256) : zz;
        float o[8];
        #pragma unroll
        for (int j = 0; j < 8; ++j) {
            float v = bf2f(vm[j]) * wreg[j * 3] + bf2f(v0[j]) * wreg[j * 3 + 1]
                    + bf2f(vp[j]) * wreg[j * 3 + 2];
            o[j] = silu(v);
        }
        us8 rb8 = { f2bf(o[0]), f2bf(o[1]), f2bf(o[2]), f2bf(o[3]),
                    f2bf(o[4]), f2bf(o[5]), f2bf(o[6]), f2bf(o[7]) };
        if (isx) {
            *(us8*)&As[r * 136 + c] = rb8;
            *(f32x4*)&xf_s[r * 132 + c]     = *(f32x4*)&o[0];
            *(f32x4*)&xf_s[r * 132 + c + 4] = *(f32x4*)&o[4];
            *(f32x4*)&xf[(size_t)gr * 128 + c]     = *(f32x4*)&o[0];
            *(f32x4*)&xf[(size_t)gr * 128 + c + 4] = *(f32x4*)&o[4];
        } else {
            *(us8*)&catb[(size_t)gr * 256 + 128 + c] = rb8;
        }
    }
    lds_barrier();
    const int lane = t & 63, wv = t >> 6;
    const int lr = lane & 15, lk = (lane >> 4) * 8;
    const int rt = (wv & 1) * 16;        // row tile base
    const int jbase = (wv >> 1) * 5;     // col-tile base (0 or 5)
    f32x4 acc[5] = {};
    #pragma unroll
    for (int kt = 0; kt < 4; ++kt) {
        const int k0 = kt * 32;
        short8 av = *(const short8*)&As[(rt + lr) * 136 + k0 + lk];
        #pragma unroll
        for (int j = 0; j < 5; ++j) {
            short8 bv = *(const short8*)(Wb + ((jbase + j) * 16 + lr) * 128 + k0 + lk);
            acc[j] = __builtin_amdgcn_mfma_f32_16x16x32_bf16(av, bv, acc[j], 0, 0, 0);
        }
    }
    lds_barrier();   // As dead -> dl_s may overlay it
    const int r0 = (lane >> 4) * 4;
    #pragma unroll
    for (int j = 0; j < 5; ++j) {
        int jj = jbase + j;
        int col = jj * 16 + lr;
        #pragma unroll
        for (int r = 0; r < 4; ++r) {
            float v = acc[j][r];
            int lrow = rt + r0 + r;
            size_t row = (size_t)m0 + lrow;
            if (jj < 8) {
                float x = v + dtb[col];
                float sp = (x > 20.f) ? x : __logf(1.f + __expf(x));
                delta[row * 128 + col] = sp;
                if (FUSE_SCAN) dl_s[lrow * 132 + col] = sp;
            } else {
                BC[row * 32 + (col - 128)] = v;
                if (FUSE_SCAN && jj == 8) bc_s[lrow * 16 + lr] = v;   // B rows for scan
            }
        }
    }
    if (!FUSE_SCAN) return;

    // ---- scan phase-1 for this block's chunk; n split across thread halves; all-LDS reads ----
    lds_barrier();
    const int hh = t >> 7, tl = t & 127;
    const int sb = m0 >> 12;
    const int ch = (m0 & 4095) >> 5;
    float Ar[8];
    #pragma unroll
    for (int n = 0; n < 8; ++n) Ar[n] = -__expf(alog[tl * 16 + hh * 8 + n]) * LOG2E;
    float h[8], p[8];
    #pragma unroll
    for (int n = 0; n < 8; ++n) { h[n] = 0.f; p[n] = 1.f; }
    #pragma unroll 4
    for (int i = 0; i < CH1; ++i) {
        float dt = dl_s[i * 132 + tl];
        float du = dt * xf_s[i * 132 + tl];
        float bl[8];
        *(f32x4*)&bl[0] = *(const f32x4*)&bc_s[i * 16 + hh * 8];
        *(f32x4*)&bl[4] = *(const f32x4*)&bc_s[i * 16 + hh * 8 + 4];
        #pragma unroll
        for (int n = 0; n < 8; ++n) {
            float a = exp2f(dt * Ar[n]);
            h[n] = fmaf(a, h[n], du * bl[n]);
            p[n] *= a;
        }
    }
    size_t ob = (((size_t)sb * NCH + ch) * 128 + tl) * 16 + hh * 8;
    f32x4 pv0 = { p[0], p[1], p[2], p[3] };
    f32x4 pv1 = { p[4], p[5], p[6], p[7] };
    f32x4 hv0 = { h[0], h[1], h[2], h[3] };
    f32x4 hv1 = { h[4], h[5], h[6], h[7] };
    *(f32x4*)&P[ob]     = pv0;
    *(f32x4*)&P[ob + 4] = pv1;
    *(f32x4*)&H[ob]     = hv0;
    *(f32x4*)&H[ob + 4] = hv1;
}

// ---------------- selective scan, chunked 3-phase (standalone p1 = fallback) ----------------
__global__ __launch_bounds__(128) void scan_p1(
    const float* __restrict__ delta, const float* __restrict__ xf,
    const float* __restrict__ BC, const float* __restrict__ alog,
    float* __restrict__ P, float* __restrict__ H)
{
    __shared__ float b_s[CH1 * 16];
    int t = threadIdx.x;                 // d channel
    int ch = blockIdx.x, sb = blockIdx.y;
    size_t rb = (size_t)sb * LL + (size_t)ch * CH1;
    {
        int row = t >> 2, c4 = (t & 3) * 4;
        *(f32x4*)&b_s[row * 16 + c4] = *(const f32x4*)&BC[(rb + row) * 32 + c4];
    }
    lds_barrier();
    float Ar[16];
    #pragma unroll
    for (int n = 0; n < 16; ++n) Ar[n] = -__expf(alog[t * 16 + n]) * LOG2E;
    float dtr[32], ur[32];
    #pragma unroll
    for (int i = 0; i < 32; ++i) dtr[i] = delta[(rb + i) * DH + t];
    #pragma unroll
    for (int i = 0; i < 32; ++i) ur[i] = xf[(rb + i) * DH + t];
    float h[16], p[16];
    #pragma unroll
    for (int n = 0; n < 16; ++n) { h[n] = 0.f; p[n] = 1.f; }
    for (int i = 0; i < CH1; ++i) {
        float dt = dtr[i];
        float du = dt * ur[i];
        float bl[16];
        *(f32x4*)&bl[0]  = *(const f32x4*)&b_s[i * 16];
        *(f32x4*)&bl[4]  = *(const f32x4*)&b_s[i * 16 + 4];
        *(f32x4*)&bl[8]  = *(const f32x4*)&b_s[i * 16 + 8];
        *(f32x4*)&bl[12] = *(const f32x4*)&b_s[i * 16 + 12];
        #pragma unroll
        for (int n = 0; n < 16; ++n) {
            float a = exp2f(dt * Ar[n]);
            h[n] = fmaf(a, h[n], du * bl[n]);
            p[n] *= a;
        }
    }
    size_t ob = (((size_t)sb * NCH + ch) * 128 + t) * 16;
    #pragma unroll
    for (int n4 = 0; n4 < 16; n4 += 4) {
        f32x4 pv = { p[n4], p[n4 + 1], p[n4 + 2], p[n4 + 3] };
        f32x4 hv = { h[n4], h[n4 + 1], h[n4 + 2], h[n4 + 3] };
        *(f32x4*)&P[ob + n4] = pv;
        *(f32x4*)&H[ob + n4] = hv;
    }
}

__global__ __launch_bounds__(256) void scan_p2(const float* __restrict__ P, float* __restrict__ H)
{
    __shared__ float Ps[NCH * 16], Hs[NCH * 16];
    int t = threadIdx.x;
    int d = blockIdx.x, sb = blockIdx.y;
    for (int q = t; q < NCH * 4; q += 256) {
        int ch = q >> 2, c4 = (q & 3) * 4;
        size_t g = (((size_t)sb * NCH + ch) * 128 + d) * 16 + c4;
        *(f32x4*)&Ps[ch * 16 + c4] = *(const f32x4*)&P[g];
        *(f32x4*)&Hs[ch * 16 + c4] = *(const f32x4*)&H[g];
    }
    lds_barrier();
    if (t < 16) {
        float hin = 0.f;
        for (int c = 0; c < NCH; ++c) {
            float pp = Ps[c * 16 + t], hl = Hs[c * 16 + t];
            Hs[c * 16 + t] = hin;
            hin = fmaf(pp, hin, hl);
        }
    }
    lds_barrier();
    for (int q = t; q < NCH * 4; q += 256) {
        int ch = q >> 2, c4 = (q & 3) * 4;
        size_t g = (((size_t)sb * NCH + ch) * 128 + d) * 16 + c4;
        *(f32x4*)&H[g] = *(const f32x4*)&Hs[ch * 16 + c4];
    }
}

// phase 3: replay with h_init; dt AND u register-prefetched before the serial loop
__global__ __launch_bounds__(128) void scan_p3(
    const float* __restrict__ delta, const float* __restrict__ xf,
    const float* __restrict__ BC, const float* __restrict__ alog,
    const float* __restrict__ Dp, const float* __restrict__ H,
    unsigned short* __restrict__ catb)
{
    __shared__ float b_s[CH1 * 16];
    __shared__ float c_s[CH1 * 16];
    int t = threadIdx.x;
    int ch = blockIdx.x, sb = blockIdx.y;
    size_t rb = (size_t)sb * LL + (size_t)ch * CH1;
    {
        int row = t >> 2, c4 = (t & 3) * 4;
        *(f32x4*)&b_s[row * 16 + c4] = *(const f32x4*)&BC[(rb + row) * 32 + c4];
        *(f32x4*)&c_s[row * 16 + c4] = *(const f32x4*)&BC[(rb + row) * 32 + 16 + c4];
    }
    lds_barrier();
    float Ar[16];
    #pragma unroll
    for (int n = 0; n < 16; ++n) Ar[n] = -__expf(alog[t * 16 + n]) * LOG2E;
    float Dv = Dp[t];
    float dtr[32], ur[32];
    #pragma unroll
    for (int i = 0; i < 32; ++i) dtr[i] = delta[(rb + i) * DH + t];
    #pragma unroll
    for (int i = 0; i < 32; ++i) ur[i] = xf[(rb + i) * DH + t];
    size_t ob = (((size_t)sb * NCH + ch) * 128 + t) * 16;
    float h[16];
    #pragma unroll
    for (int n4 = 0; n4 < 16; n4 += 4) {
        f32x4 hv = *(const f32x4*)&H[ob + n4];
        h[n4] = hv.x; h[n4 + 1] = hv.y; h[n4 + 2] = hv.z; h[n4 + 3] = hv.w;
    }
    for (int i = 0; i < CH1; ++i) {
        float dt = dtr[i];
        float uu = ur[i];
        float du = dt * uu;
        float bl[16], cl[16];
        *(f32x4*)&bl[0]  = *(const f32x4*)&b_s[i * 16];
        *(f32x4*)&bl[4]  = *(const f32x4*)&b_s[i * 16 + 4];
        *(f32x4*)&bl[8]  = *(const f32x4*)&b_s[i * 16 + 8];
        *(f32x4*)&bl[12] = *(const f32x4*)&b_s[i * 16 + 12];
        *(f32x4*)&cl[0]  = *(const f32x4*)&c_s[i * 16];
        *(f32x4*)&cl[4]  = *(const f32x4*)&c_s[i * 16 + 4];
        *(f32x4*)&cl[8]  = *(const f32x4*)&c_s[i * 16 + 8];
        *(f32x4*)&cl[12] = *(const f32x4*)&c_s[i * 16 + 12];
        float y0 = uu * Dv, y1 = 0.f, y2 = 0.f, y3 = 0.f;
        #pragma unroll
        for (int n = 0; n < 16; n += 4) {
            float a0 = exp2f(dt * Ar[n]);
            float a1 = exp2f(dt * Ar[n + 1]);
            float a2 = exp2f(dt * Ar[n + 2]);
            float a3 = exp2f(dt * Ar[n + 3]);
            h[n]     = fmaf(a0, h[n],     du * bl[n]);
            h[n + 1] = fmaf(a1, h[n + 1], du * bl[n + 1]);
            h[n + 2] = fmaf(a2, h[n + 2], du * bl[n + 2]);
            h[n + 3] = fmaf(a3, h[n + 3], du * bl[n + 3]);
            y0 = fmaf(h[n],     cl[n],     y0);
            y1 = fmaf(h[n + 1], cl[n + 1], y1);
            y2 = fmaf(h[n + 2], cl[n + 2], y2);
            y3 = fmaf(h[n + 3], cl[n + 3], y3);
        }
        float y = (y0 + y1) + (y2 + y3);
        catb[(rb + i) * DM + t] = f2bf(y);
    }
}

extern "C" void kernel_launch(void* const* d_in, const int* in_sizes, int n_in,
                              void* d_out, int out_size, void* d_ws, size_t ws_size,
                              hipStream_t stream) {
    const float* u0   = (const float*)d_in[0];
    const float* u1   = (const float*)d_in[1];
    const float* inw  = (const float*)d_in[2];
    const float* cxw  = (const float*)d_in[3];
    const float* czw  = (const float*)d_in[4];
    const float* xpw  = (const float*)d_in[5];
    const float* dtw  = (const float*)d_in[6];
    const float* dtb  = (const float*)d_in[7];
    const float* alog = (const float*)d_in[8];
    const float* Dp   = (const float*)d_in[9];
    const float* outw = (const float*)d_in[10];

    // Layout (same as R6-R12):
    //   [0 : 16.8M]      ubf (prep->gemm1), then delta (convproj..scan_p3)
    //   [16.8M : 33.6M]  xzbf (gemm1->convproj)   [fallback: then P/H]
    //   [33.6M : 50.3M]  xf f32
    //   [50.3M : 54.5M]  BC
    //   [54.5M : 71.3M]  catb
    //   [71.3M : 71.6M]  wbi, wbo, Wb
    //   fused path: P/H fresh at [71.6M : 88.4M]
    char* ws = (char*)d_ws;
    unsigned short* ubf  = (unsigned short*)(ws + 0);
    float* delta         = (float*)(ws + 0);
    unsigned short* xzbf = (unsigned short*)(ws + 16777216);
    float* P_a           = (float*)(ws + 16777216);
    float* H_a           = (float*)(ws + 25165824);
    float* xf            = (float*)(ws + 33554432);
    float* BC            = (float*)(ws + 50331648);
    unsigned short* catb = (unsigned short*)(ws + 54525952);
    unsigned short* wbi  = (unsigned short*)(ws + 71303168);
    unsigned short* wbo  = (unsigned short*)(ws + 71434240);
    unsigned short* Wb   = (unsigned short*)(ws + 71565312);
    float* P_f           = (float*)(ws + 71606272);
    float* H_f           = (float*)(ws + 79994880);

    float* outp = (float*)d_out;

    prep_kernel<<<8340, 256, 0, stream>>>(u0, u1, inw, outw, xpw, dtw, ubf, wbi, wbo, Wb);
    gemm_bt<0><<<dim3(256, 2), 256, 0, stream>>>(ubf, wbi, nullptr, xzbf);

    if (ws_size >= 88383488ull) {
        convproj_k<1><<<1024, 256, 0, stream>>>(xzbf, Wb, cxw, czw, dtb, alog,
                                                xf, catb, delta, BC, P_f, H_f);
        scan_p2<<<dim3(128, 8), 256, 0, stream>>>(P_f, H_f);
        scan_p3<<<dim3(NCH, 8), 128, 0, stream>>>(delta, xf, BC, alog, Dp, H_f, catb);
    } else {
        convproj_k<0><<<1024, 256, 0, stream>>>(xzbf, Wb, cxw, czw, dtb, alog,
                                                xf, catb, delta, BC, nullptr, nullptr);
        scan_p1<<<dim3(NCH, 8), 128, 0, stream>>>(delta, xf, BC, alog, P_a, H_a);
        scan_p2<<<dim3(128, 8), 256, 0, stream>>>(P_a, H_a);
        scan_p3<<<dim3(NCH, 8), 128, 0, stream>>>(delta, xf, BC, alog, Dp, H_a, catb);
    }
    gemm_bt<1><<<dim3(256, 2), 256, 0, stream>>>(catb, wbo, outp, nullptr);
}

// Round 14
// 192.965 us; speedup vs baseline: 1.1849x; 1.1011x over previous
//
#include <hip/hip_runtime.h>
#include <hip/hip_bf16.h>
#include <cstdint>

#define DEV __device__ __forceinline__

typedef __attribute__((ext_vector_type(8))) short short8;
typedef __attribute__((ext_vector_type(4))) float f32x4;
typedef __attribute__((ext_vector_type(4))) unsigned short us4;
typedef __attribute__((ext_vector_type(8))) unsigned short us8;

DEV unsigned short f2bf(float x) {
    unsigned int u = __float_as_uint(x);
    unsigned int r = (u + 0x7FFFu + ((u >> 16) & 1u)) >> 16;
    return (unsigned short)r;
}
DEV float bf2f(unsigned short h) { return __uint_as_float(((unsigned int)h) << 16); }

// async global->LDS, 16B per lane; LDS dest is wave-uniform base + lane*16 (HW rule)
DEV void gld_lds16(const unsigned short* g, unsigned short* l) {
    __builtin_amdgcn_global_load_lds(
        (const __attribute__((address_space(1))) unsigned int*)g,
        (__attribute__((address_space(3))) unsigned int*)l, 16, 0, 0);
}

// SiLU with fast division (v_rcp_f32 path; error below bf16 rounding)
DEV float silu(float v) {
    return __fdividef(v, 1.f + __expf(-v));
}

// raw hardware exp2: single v_exp_f32 (libm exp2f is a multi-instruction
// denormal-safe sequence; ~1ulp difference, far below bf16 rounding).
DEV float fexp2(float x) {
    float r;
    asm("v_exp_f32 %0, %1" : "=v"(r) : "v"(x));
    return r;
}

// LDS-only barrier: orders LDS ops across waves WITHOUT draining outstanding
// global stores. Safe when all cross-wave deps at the barrier are through LDS.
DEV void lds_barrier() {
    __builtin_amdgcn_sched_barrier(0);
    asm volatile("s_waitcnt lgkmcnt(0)" ::: "memory");
    __builtin_amdgcn_s_barrier();
    __builtin_amdgcn_sched_barrier(0);
}

// problem sizes
#define LL 4096
#define DM 256
#define DH 128
#define SB_TOT 8       // 2 streams * 4 batch
#define CH1 32         // scan chunk length
#define NCH 128        // LL / CH1
#define LOG2E 1.44269504088896f

// ---------------- prep: fp32 -> bf16 (u, in_proj, out_proj) + fused proj weight Wb ----------------
__global__ __launch_bounds__(256) void prep_kernel(
    const float* __restrict__ u0, const float* __restrict__ u1,
    const float* __restrict__ inw, const float* __restrict__ outw,
    const float* __restrict__ xpw, const float* __restrict__ dtw,
    unsigned short* __restrict__ ubf, unsigned short* __restrict__ wbi,
    unsigned short* __restrict__ wbo, unsigned short* __restrict__ Wb)
{
    int gid = blockIdx.x * 256 + threadIdx.x;
    int i = gid * 4;
    if (i < 4194304) {
        f32x4 v = *(const f32x4*)&u0[i];
        us4 r = { f2bf(v.x), f2bf(v.y), f2bf(v.z), f2bf(v.w) };
        *(us4*)&ubf[i] = r;
    } else if (i < 8388608) {
        int j = i - 4194304;
        f32x4 v = *(const f32x4*)&u1[j];
        us4 r = { f2bf(v.x), f2bf(v.y), f2bf(v.z), f2bf(v.w) };
        *(us4*)&ubf[4194304 + j] = r;
    } else if (i < 8454144) {
        int j = i - 8388608;
        f32x4 v = *(const f32x4*)&inw[j];
        us4 r = { f2bf(v.x), f2bf(v.y), f2bf(v.z), f2bf(v.w) };
        *(us4*)&wbi[j] = r;
    } else if (i < 8519680) {
        int j = i - 8454144;
        f32x4 v = *(const f32x4*)&outw[j];
        us4 r = { f2bf(v.x), f2bf(v.y), f2bf(v.z), f2bf(v.w) };
        *(us4*)&wbo[j] = r;
    } else if (i < 8540160) {
        int j = i - 8519680;            // 0..20476, step 4
        int n = j >> 7, k0 = j & 127;
        if (n < 128) {
            float a0 = 0.f, a1 = 0.f, a2 = 0.f, a3 = 0.f;
            const float* dw = dtw + n * 16;
            #pragma unroll
            for (int r = 0; r < 16; ++r) {
                float w = dw[r];
                const float* xr = xpw + r * 128 + k0;
                a0 = fmaf(w, xr[0], a0);
                a1 = fmaf(w, xr[1], a1);
                a2 = fmaf(w, xr[2], a2);
                a3 = fmaf(w, xr[3], a3);
            }
            us4 rr = { f2bf(a0), f2bf(a1), f2bf(a2), f2bf(a3) };
            *(us4*)&Wb[n * 128 + k0] = rr;
        } else {
            f32x4 v = *(const f32x4*)&xpw[(n - 112) * 128 + k0];
            us4 rr = { f2bf(v.x), f2bf(v.y), f2bf(v.z), f2bf(v.w) };
            *(us4*)&Wb[n * 128 + k0] = rr;
        }
    }
}

// ---------------- bf16 MFMA GEMM (m97 structure): C[M,N] = A[M,K] * B[N,K]^T, K=N=256 ----------------
template<int F32OUT>
__global__ __launch_bounds__(256) void gemm_bt(
    const unsigned short* __restrict__ A, const unsigned short* __restrict__ B,
    float* __restrict__ Cf, unsigned short* __restrict__ Cb)
{
    __shared__ __align__(16) unsigned short As[128 * 32];
    __shared__ __align__(16) unsigned short Bs[128 * 32];
    const int t = threadIdx.x;
    const int m0 = blockIdx.x * 128, n0 = blockIdx.y * 128;
    const int lane = t & 63, wv = t >> 6;
    const int wm = (wv & 1) * 64, wn = (wv >> 1) * 64;
    const int lr = lane & 15, lk = (lane >> 4) * 8;
    const int srow = lane >> 2, scol = (lane & 3) * 8;

    f32x4 acc[4][4] = {};
    for (int kt = 0; kt < 8; ++kt) {
        const int k0 = kt * 32;
        #pragma unroll
        for (int h = 0; h < 2; ++h) {
            const int c = wv + h * 4;
            const unsigned short* ga = A + (size_t)(m0 + c * 16 + srow) * 256 + k0 + scol;
            const unsigned short* gb = B + (size_t)(n0 + c * 16 + srow) * 256 + k0 + scol;
            gld_lds16(ga, &As[c * 512]);
            gld_lds16(gb, &Bs[c * 512]);
        }
        __syncthreads();
        short8 av[4], bv[4];
        #pragma unroll
        for (int i = 0; i < 4; ++i) av[i] = *(const short8*)&As[(wm + i * 16 + lr) * 32 + lk];
        #pragma unroll
        for (int i = 0; i < 4; ++i) bv[i] = *(const short8*)&Bs[(wn + i * 16 + lr) * 32 + lk];
        #pragma unroll
        for (int i = 0; i < 4; ++i)
            #pragma unroll
            for (int j = 0; j < 4; ++j)
                acc[i][j] = __builtin_amdgcn_mfma_f32_16x16x32_bf16(av[i], bv[j], acc[i][j], 0, 0, 0);
        __syncthreads();
    }
    #pragma unroll
    for (int i = 0; i < 4; ++i) {
        #pragma unroll
        for (int j = 0; j < 4; ++j) {
            int r0 = m0 + wm + i * 16 + (lane >> 4) * 4;
            int cc = n0 + wn + j * 16 + lr;
            #pragma unroll
            for (int r = 0; r < 4; ++r) {
                float v = acc[i][j][r];
                if (F32OUT) Cf[(size_t)(r0 + r) * 256 + cc] = v;
                else        Cb[(size_t)(r0 + r) * 256 + cc] = f2bf(v);
            }
        }
    }
}

// ---------------- fused depthwise conv + SiLU + proj MFMA + softplus + scan-p1 ----------------
// BM=32, grid 1024. All barriers are LDS-only; scan exp2 is raw v_exp_f32.
template<int FUSE_SCAN>
__global__ __launch_bounds__(256) void convproj_k(
    const unsigned short* __restrict__ xz, const unsigned short* __restrict__ Wb,
    const float* __restrict__ wx, const float* __restrict__ wz,
    const float* __restrict__ dtb, const float* __restrict__ alog,
    float* __restrict__ xf, unsigned short* __restrict__ catb,
    float* __restrict__ delta, float* __restrict__ BC,
    float* __restrict__ P, float* __restrict__ H)
{
    // smem: [0:16896) union{ As[32][136] bf16 (8704B) | dl_s[32][132] f32 }
    //       [16896:33792) xf_s[32][132] f32 ; [33792:35840) bc_s[32][16] f32
    __shared__ __align__(16) char smem[35840];
    unsigned short* As = (unsigned short*)smem;
    float* dl_s = (float*)smem;
    float* xf_s = (float*)(smem + 16896);
    float* bc_s = (float*)(smem + 33792);
    const int t = threadIdx.x;
    // bijective XCD-aligned mapping (rows this block reads were produced on its XCD)
    const int kk = blockIdx.x & 7, yy = blockIdx.x >> 3;
    const int m0 = (4 * kk + (yy & 3) + 32 * (yy >> 2)) * 32;

    // conv: g,c invariant across the 4 row-iterations -> hoist weight loads
    const int gg = t & 31;
    const bool isx = gg < 16;
    const int c = (isx ? gg : gg - 16) * 8;
    const float* wp = isx ? wx : wz;
    float wreg[24];
    #pragma unroll
    for (int j = 0; j < 6; ++j) *(f32x4*)&wreg[j * 4] = *(const f32x4*)(wp + c * 3 + j * 4);
    #pragma unroll
    for (int i = 0; i < 4; ++i) {
        int r = (t >> 5) + i * 8;
        int gr = m0 + r;
        int l = gr & 4095;
        const unsigned short* bp = xz + (size_t)gr * 256 + (isx ? c : 128 + c);
        us8 zz = (us8)0;
        us8 vm = (l > 0)    ? *(const us8*)(bp - 256) : zz;
        us8 v0 = *(const us8*)bp;
        us8 vp = (l < 4095) ? *(const us8*)(bp + 256) : zz;
        float o[8];
        #pragma unroll
        for (int j = 0; j < 8; ++j) {
            float v = bf2f(vm[j]) * wreg[j * 3] + bf2f(v0[j]) * wreg[j * 3 + 1]
                    + bf2f(vp[j]) * wreg[j * 3 + 2];
            o[j] = silu(v);
        }
        us8 rb8 = { f2bf(o[0]), f2bf(o[1]), f2bf(o[2]), f2bf(o[3]),
                    f2bf(o[4]), f2bf(o[5]), f2bf(o[6]), f2bf(o[7]) };
        if (isx) {
            *(us8*)&As[r * 136 + c] = rb8;
            *(f32x4*)&xf_s[r * 132 + c]     = *(f32x4*)&o[0];
            *(f32x4*)&xf_s[r * 132 + c + 4] = *(f32x4*)&o[4];
            *(f32x4*)&xf[(size_t)gr * 128 + c]     = *(f32x4*)&o[0];
            *(f32x4*)&xf[(size_t)gr * 128 + c + 4] = *(f32x4*)&o[4];
        } else {
            *(us8*)&catb[(size_t)gr * 256 + 128 + c] = rb8;
        }
    }
    lds_barrier();
    const int lane = t & 63, wv = t >> 6;
    const int lr = lane & 15, lk = (lane >> 4) * 8;
    const int rt = (wv & 1) * 16;        // row tile base
    const int jbase = (wv >> 1) * 5;     // col-tile base (0 or 5)
    f32x4 acc[5] = {};
    #pragma unroll
    for (int kt = 0; kt < 4; ++kt) {
        const int k0 = kt * 32;
        short8 av = *(const short8*)&As[(rt + lr) * 136 + k0 + lk];
        #pragma unroll
        for (int j = 0; j < 5; ++j) {
            short8 bv = *(const short8*)(Wb + ((jbase + j) * 16 + lr) * 128 + k0 + lk);
            acc[j] = __builtin_amdgcn_mfma_f32_16x16x32_bf16(av, bv, acc[j], 0, 0, 0);
        }
    }
    lds_barrier();   // As dead -> dl_s may overlay it
    const int r0 = (lane >> 4) * 4;
    #pragma unroll
    for (int j = 0; j < 5; ++j) {
        int jj = jbase + j;
        int col = jj * 16 + lr;
        #pragma unroll
        for (int r = 0; r < 4; ++r) {
            float v = acc[j][r];
            int lrow = rt + r0 + r;
            size_t row = (size_t)m0 + lrow;
            if (jj < 8) {
                float x = v + dtb[col];
                float sp = (x > 20.f) ? x : __logf(1.f + __expf(x));
                delta[row * 128 + col] = sp;
                if (FUSE_SCAN) dl_s[lrow * 132 + col] = sp;
            } else {
                BC[row * 32 + (col - 128)] = v;
                if (FUSE_SCAN && jj == 8) bc_s[lrow * 16 + lr] = v;   // B rows for scan
            }
        }
    }
    if (!FUSE_SCAN) return;

    // ---- scan phase-1 for this block's chunk; n split across thread halves; all-LDS reads ----
    lds_barrier();
    const int hh = t >> 7, tl = t & 127;
    const int sb = m0 >> 12;
    const int ch = (m0 & 4095) >> 5;
    float Ar[8];
    #pragma unroll
    for (int n = 0; n < 8; ++n) Ar[n] = -__expf(alog[tl * 16 + hh * 8 + n]) * LOG2E;
    float h[8], p[8];
    #pragma unroll
    for (int n = 0; n < 8; ++n) { h[n] = 0.f; p[n] = 1.f; }
    #pragma unroll 4
    for (int i = 0; i < CH1; ++i) {
        float dt = dl_s[i * 132 + tl];
        float du = dt * xf_s[i * 132 + tl];
        float bl[8];
        *(f32x4*)&bl[0] = *(const f32x4*)&bc_s[i * 16 + hh * 8];
        *(f32x4*)&bl[4] = *(const f32x4*)&bc_s[i * 16 + hh * 8 + 4];
        #pragma unroll
        for (int n = 0; n < 8; ++n) {
            float a = fexp2(dt * Ar[n]);
            h[n] = fmaf(a, h[n], du * bl[n]);
            p[n] *= a;
        }
    }
    size_t ob = (((size_t)sb * NCH + ch) * 128 + tl) * 16 + hh * 8;
    f32x4 pv0 = { p[0], p[1], p[2], p[3] };
    f32x4 pv1 = { p[4], p[5], p[6], p[7] };
    f32x4 hv0 = { h[0], h[1], h[2], h[3] };
    f32x4 hv1 = { h[4], h[5], h[6], h[7] };
    *(f32x4*)&P[ob]     = pv0;
    *(f32x4*)&P[ob + 4] = pv1;
    *(f32x4*)&H[ob]     = hv0;
    *(f32x4*)&H[ob + 4] = hv1;
}

// ---------------- selective scan, chunked 3-phase (standalone p1 = fallback) ----------------
__global__ __launch_bounds__(128) void scan_p1(
    const float* __restrict__ delta, const float* __restrict__ xf,
    const float* __restrict__ BC, const float* __restrict__ alog,
    float* __restrict__ P, float* __restrict__ H)
{
    __shared__ float b_s[CH1 * 16];
    int t = threadIdx.x;                 // d channel
    int ch = blockIdx.x, sb = blockIdx.y;
    size_t rb = (size_t)sb * LL + (size_t)ch * CH1;
    {
        int row = t >> 2, c4 = (t & 3) * 4;
        *(f32x4*)&b_s[row * 16 + c4] = *(const f32x4*)&BC[(rb + row) * 32 + c4];
    }
    lds_barrier();
    float Ar[16];
    #pragma unroll
    for (int n = 0; n < 16; ++n) Ar[n] = -__expf(alog[t * 16 + n]) * LOG2E;
    float dtr[32], ur[32];
    #pragma unroll
    for (int i = 0; i < 32; ++i) dtr[i] = delta[(rb + i) * DH + t];
    #pragma unroll
    for (int i = 0; i < 32; ++i) ur[i] = xf[(rb + i) * DH + t];
    float h[16], p[16];
    #pragma unroll
    for (int n = 0; n < 16; ++n) { h[n] = 0.f; p[n] = 1.f; }
    for (int i = 0; i < CH1; ++i) {
        float dt = dtr[i];
        float du = dt * ur[i];
        float bl[16];
        *(f32x4*)&bl[0]  = *(const f32x4*)&b_s[i * 16];
        *(f32x4*)&bl[4]  = *(const f32x4*)&b_s[i * 16 + 4];
        *(f32x4*)&bl[8]  = *(const f32x4*)&b_s[i * 16 + 8];
        *(f32x4*)&bl[12] = *(const f32x4*)&b_s[i * 16 + 12];
        #pragma unroll
        for (int n = 0; n < 16; ++n) {
            float a = fexp2(dt * Ar[n]);
            h[n] = fmaf(a, h[n], du * bl[n]);
            p[n] *= a;
        }
    }
    size_t ob = (((size_t)sb * NCH + ch) * 128 + t) * 16;
    #pragma unroll
    for (int n4 = 0; n4 < 16; n4 += 4) {
        f32x4 pv = { p[n4], p[n4 + 1], p[n4 + 2], p[n4 + 3] };
        f32x4 hv = { h[n4], h[n4 + 1], h[n4 + 2], h[n4 + 3] };
        *(f32x4*)&P[ob + n4] = pv;
        *(f32x4*)&H[ob + n4] = hv;
    }
}

__global__ __launch_bounds__(256) void scan_p2(const float* __restrict__ P, float* __restrict__ H)
{
    __shared__ float Ps[NCH * 16], Hs[NCH * 16];
    int t = threadIdx.x;
    int d = blockIdx.x, sb = blockIdx.y;
    for (int q = t; q < NCH * 4; q += 256) {
        int ch = q >> 2, c4 = (q & 3) * 4;
        size_t g = (((size_t)sb * NCH + ch) * 128 + d) * 16 + c4;
        *(f32x4*)&Ps[ch * 16 + c4] = *(const f32x4*)&P[g];
        *(f32x4*)&Hs[ch * 16 + c4] = *(const f32x4*)&H[g];
    }
    lds_barrier();
    if (t < 16) {
        float hin = 0.f;
        for (int c = 0; c < NCH; ++c) {
            float pp = Ps[c * 16 + t], hl = Hs[c * 16 + t];
            Hs[c * 16 + t] = hin;
            hin = fmaf(pp, hin, hl);
        }
    }
    lds_barrier();
    for (int q = t; q < NCH * 4; q += 256) {
        int ch = q >> 2, c4 = (q & 3) * 4;
        size_t g = (((size_t)sb * NCH + ch) * 128 + d) * 16 + c4;
        *(f32x4*)&H[g] = *(const f32x4*)&Hs[ch * 16 + c4];
    }
}

// phase 3: replay with h_init; dt AND u register-prefetched; raw v_exp_f32
__global__ __launch_bounds__(128) void scan_p3(
    const float* __restrict__ delta, const float* __restrict__ xf,
    const float* __restrict__ BC, const float* __restrict__ alog,
    const float* __restrict__ Dp, const float* __restrict__ H,
    unsigned short* __restrict__ catb)
{
    __shared__ float b_s[CH1 * 16];
    __shared__ float c_s[CH1 * 16];
    int t = threadIdx.x;
    int ch = blockIdx.x, sb = blockIdx.y;
    size_t rb = (size_t)sb * LL + (size_t)ch * CH1;
    {
        int row = t >> 2, c4 = (t & 3) * 4;
        *(f32x4*)&b_s[row * 16 + c4] = *(const f32x4*)&BC[(rb + row) * 32 + c4];
        *(f32x4*)&c_s[row * 16 + c4] = *(const f32x4*)&BC[(rb + row) * 32 + 16 + c4];
    }
    lds_barrier();
    float Ar[16];
    #pragma unroll
    for (int n = 0; n < 16; ++n) Ar[n] = -__expf(alog[t * 16 + n]) * LOG2E;
    float Dv = Dp[t];
    float dtr[32], ur[32];
    #pragma unroll
    for (int i = 0; i < 32; ++i) dtr[i] = delta[(rb + i) * DH + t];
    #pragma unroll
    for (int i = 0; i < 32; ++i) ur[i] = xf[(rb + i) * DH + t];
    size_t ob = (((size_t)sb * NCH + ch) * 128 + t) * 16;
    float h[16];
    #pragma unroll
    for (int n4 = 0; n4 < 16; n4 += 4) {
        f32x4 hv = *(const f32x4*)&H[ob + n4];
        h[n4] = hv.x; h[n4 + 1] = hv.y; h[n4 + 2] = hv.z; h[n4 + 3] = hv.w;
    }
    for (int i = 0; i < CH1; ++i) {
        float dt = dtr[i];
        float uu = ur[i];
        float du = dt * uu;
        float bl[16], cl[16];
        *(f32x4*)&bl[0]  = *(const f32x4*)&b_s[i * 16];
        *(f32x4*)&bl[4]  = *(const f32x4*)&b_s[i * 16 + 4];
        *(f32x4*)&bl[8]  = *(const f32x4*)&b_s[i * 16 + 8];
        *(f32x4*)&bl[12] = *(const f32x4*)&b_s[i * 16 + 12];
        *(f32x4*)&cl[0]  = *(const f32x4*)&c_s[i * 16];
        *(f32x4*)&cl[4]  = *(const f32x4*)&c_s[i * 16 + 4];
        *(f32x4*)&cl[8]  = *(const f32x4*)&c_s[i * 16 + 8];
        *(f32x4*)&cl[12] = *(const f32x4*)&c_s[i * 16 + 12];
        float y0 = uu * Dv, y1 = 0.f, y2 = 0.f, y3 = 0.f;
        #pragma unroll
        for (int n = 0; n < 16; n += 4) {
            float a0 = fexp2(dt * Ar[n]);
            float a1 = fexp2(dt * Ar[n + 1]);
            float a2 = fexp2(dt * Ar[n + 2]);
            float a3 = fexp2(dt * Ar[n + 3]);
            h[n]     = fmaf(a0, h[n],     du * bl[n]);
            h[n + 1] = fmaf(a1, h[n + 1], du * bl[n + 1]);
            h[n + 2] = fmaf(a2, h[n + 2], du * bl[n + 2]);
            h[n + 3] = fmaf(a3, h[n + 3], du * bl[n + 3]);
            y0 = fmaf(h[n],     cl[n],     y0);
            y1 = fmaf(h[n + 1], cl[n + 1], y1);
            y2 = fmaf(h[n + 2], cl[n + 2], y2);
            y3 = fmaf(h[n + 3], cl[n + 3], y3);
        }
        float y = (y0 + y1) + (y2 + y3);
        catb[(rb + i) * DM + t] = f2bf(y);
    }
}

extern "C" void kernel_launch(void* const* d_in, const int* in_sizes, int n_in,
                              void* d_out, int out_size, void* d_ws, size_t ws_size,
                              hipStream_t stream) {
    const float* u0   = (const float*)d_in[0];
    const float* u1   = (const float*)d_in[1];
    const float* inw  = (const float*)d_in[2];
    const float* cxw  = (const float*)d_in[3];
    const float* czw  = (const float*)d_in[4];
    const float* xpw  = (const float*)d_in[5];
    const float* dtw  = (const float*)d_in[6];
    const float* dtb  = (const float*)d_in[7];
    const float* alog = (const float*)d_in[8];
    const float* Dp   = (const float*)d_in[9];
    const float* outw = (const float*)d_in[10];

    // Layout (same as R6-R13):
    //   [0 : 16.8M]      ubf (prep->gemm1), then delta (convproj..scan_p3)
    //   [16.8M : 33.6M]  xzbf (gemm1->convproj)   [fallback: then P/H]
    //   [33.6M : 50.3M]  xf f32
    //   [50.3M : 54.5M]  BC
    //   [54.5M : 71.3M]  catb
    //   [71.3M : 71.6M]  wbi, wbo, Wb
    //   fused path: P/H fresh at [71.6M : 88.4M]
    char* ws = (char*)d_ws;
    unsigned short* ubf  = (unsigned short*)(ws + 0);
    float* delta         = (float*)(ws + 0);
    unsigned short* xzbf = (unsigned short*)(ws + 16777216);
    float* P_a           = (float*)(ws + 16777216);
    float* H_a           = (float*)(ws + 25165824);
    float* xf            = (float*)(ws + 33554432);
    float* BC            = (float*)(ws + 50331648);
    unsigned short* catb = (unsigned short*)(ws + 54525952);
    unsigned short* wbi  = (unsigned short*)(ws + 71303168);
    unsigned short* wbo  = (unsigned short*)(ws + 71434240);
    unsigned short* Wb   = (unsigned short*)(ws + 71565312);
    float* P_f           = (float*)(ws + 71606272);
    float* H_f           = (float*)(ws + 79994880);

    float* outp = (float*)d_out;

    prep_kernel<<<8340, 256, 0, stream>>>(u0, u1, inw, outw, xpw, dtw, ubf, wbi, wbo, Wb);
    gemm_bt<0><<<dim3(256, 2), 256, 0, stream>>>(ubf, wbi, nullptr, xzbf);

    if (ws_size >= 88383488ull) {
        convproj_k<1><<<1024, 256, 0, stream>>>(xzbf, Wb, cxw, czw, dtb, alog,
                                                xf, catb, delta, BC, P_f, H_f);
        scan_p2<<<dim3(128, 8), 256, 0, stream>>>(P_f, H_f);
        scan_p3<<<dim3(NCH, 8), 128, 0, stream>>>(delta, xf, BC, alog, Dp, H_f, catb);
    } else {
        convproj_k<0><<<1024, 256, 0, stream>>>(xzbf, Wb, cxw, czw, dtb, alog,
                                                xf, catb, delta, BC, nullptr, nullptr);
        scan_p1<<<dim3(NCH, 8), 128, 0, stream>>>(delta, xf, BC, alog, P_a, H_a);
        scan_p2<<<dim3(128, 8), 256, 0, stream>>>(P_a, H_a);
        scan_p3<<<dim3(NCH, 8), 128, 0, stream>>>(delta, xf, BC, alog, Dp, H_a, catb);
    }
    gemm_bt<1><<<dim3(256, 2), 256, 0, stream>>>(catb, wbo, outp, nullptr);
}